// Round 2
// baseline (492.425 us; speedup 1.0000x reference)
//
#include <hip/hip_runtime.h>

typedef unsigned short u16;
typedef __attribute__((ext_vector_type(8))) short bf8;    // 8 x bf16 MFMA fragment
typedef __attribute__((ext_vector_type(4))) short s16x4;
typedef __attribute__((ext_vector_type(4))) float f32x4;
typedef __attribute__((ext_vector_type(4))) int   i32x4;

#define S_   96
#define T_   50
#define NSEQ 1536
#define NR   1537
// hidden width 256, gate width 768

__device__ __forceinline__ float bf2f(u16 u){ return __uint_as_float(((unsigned)u)<<16); }
__device__ __forceinline__ u16 f2bf(float f){
  unsigned u = __float_as_uint(f);
  u += 0x7fffu + ((u>>16)&1u);           // RNE
  return (u16)(u>>16);
}
__device__ __forceinline__ float sigm(float x){
  x = fminf(30.f, fmaxf(-30.f, x));
  return 1.f/(1.f+__expf(-x));
}
__device__ __forceinline__ float tanh_(float x){
  x = fminf(15.f, fmaxf(-15.f, x));
  float e = __expf(2.f*x);
  return (e-1.f)/(e+1.f);
}
__device__ __forceinline__ i32x4 pack8(f32x4 a, f32x4 b){
  union { s16x4 h[2]; i32x4 w; } u;
  #pragma unroll
  for (int i=0;i<4;i++){ u.h[0][i]=(short)f2bf(a[i]); u.h[1][i]=(short)f2bf(b[i]); }
  return u.w;
}

// ---------------------------------------------------------------------------
// Stage 0: convert the 10 fp32 weight matrices to bf16 copies in ws.
// sizes: 4x(512*128)=262144 | 2x(128*256)=65536 | 4x(768*256)=786432
// total 1114112 elems, 4 per thread -> 278528 threads = 1088 blocks
// ---------------------------------------------------------------------------
struct CvtArgs { const float* s[10]; u16* d[10]; };
__global__ __launch_bounds__(256) void cvt_kernel(CvtArgs a){
  int e = (blockIdx.x*256 + threadIdx.x)*4;
  if (e >= 1114112) return;
  int t, off;
  if (e < 262144){ t = e>>16; off = e & 65535; }
  else if (e < 327680){ int e2=e-262144; t = 4+(e2>>15); off = e2&32767; }
  else { int e3=e-327680; t = 6 + e3/196608; off = e3%196608; }
  f32x4 v = *reinterpret_cast<const f32x4*>(a.s[t]+off);
  s16x4 o;
  #pragma unroll
  for (int i=0;i<4;i++) o[i]=(short)f2bf(v[i]);
  *reinterpret_cast<s16x4*>(a.d[t]+off) = o;
}

// ---------------------------------------------------------------------------
// Stage 1: bidirectional LSTM final states. 16 seqs/block, 8 waves.
// K=256 ([x(128)|h(128)]), each wave owns 64 gate columns, W(bf16) in registers.
// ---------------------------------------------------------------------------
__global__ __launch_bounds__(512, 2) void lstm_kernel(
    const int* __restrict__ enc, const float* __restrict__ emb,
    const u16* __restrict__ WihF, const u16* __restrict__ WhhF, const float* __restrict__ bF,
    const u16* __restrict__ WihB, const u16* __restrict__ WhhB, const float* __restrict__ bB,
    u16* __restrict__ c_cat, u16* __restrict__ h_cat)
{
  __shared__ short xh[16*264];        // [16 rows][256 bf16 + 8 pad] : x | h
  __shared__ float gates[16*520];     // [16 rows][512 f32 + 8 pad]
  __shared__ int   toks[16*T_];

  const int tid  = threadIdx.x;
  const int wave = tid>>6;
  const int lane = tid&63;
  const int dir  = blockIdx.y;
  const int s0   = blockIdx.x*16;

  const u16* Wih = dir ? WihB : WihF;
  const u16* Whh = dir ? WhhB : WhhF;
  const float* bb = dir ? bB  : bF;

  for (int i=tid; i<16*T_; i+=512)
    toks[i] = enc[(s0 + i/T_)*T_ + (i%T_)];

  const int mL   = lane&15;
  const int quad = lane>>4;
  const int kb   = quad*8;

  // weight fragments: wave covers gate cols [wave*64, wave*64+64)
  bf8 Breg[4][8];
  float bias[4];
  #pragma unroll
  for (int n=0;n<4;n++){
    int col = wave*64 + n*16 + mL;
    bias[n] = bb[col];
    #pragma unroll
    for (int ks=0;ks<8;ks++){
      int k = ks*32 + kb;
      const u16* p = (k<128) ? (Wih + col*128 + k) : (Whh + col*128 + (k-128));
      Breg[n][ks] = *reinterpret_cast<const bf8*>(p);
    }
  }

  // zero h region
  if (tid<256){
    int r = tid>>4, c = tid&15;
    *reinterpret_cast<i32x4*>(&xh[r*264 + 128 + c*8]) = (i32x4){0,0,0,0};
  }

  const int srow = tid>>4, schunk = tid&15;   // x staging (threads <256)
  const int eseq = tid>>5, ech = (tid&31)*4;  // elementwise mapping
  float cst[4] = {0.f,0.f,0.f,0.f};
  float hst[4] = {0.f,0.f,0.f,0.f};

  __syncthreads();  // toks + zero-h visible

  f32x4 xpreA, xpreB;
  if (tid<256){
    int tt0 = dir ? (T_-1) : 0;
    int tok = toks[srow*T_ + tt0];
    const f32x4* p = reinterpret_cast<const f32x4*>(emb + tok*128 + schunk*8);
    xpreA = p[0]; xpreB = p[1];
  }

  for (int t=0;t<T_;t++){
    if (tid<256){
      *reinterpret_cast<i32x4*>(&xh[srow*264 + schunk*8]) = pack8(xpreA, xpreB);
      if (t+1 < T_){
        int tt = dir ? (T_-2-t) : (t+1);
        int tok = toks[srow*T_ + tt];
        const f32x4* p = reinterpret_cast<const f32x4*>(emb + tok*128 + schunk*8);
        xpreA = p[0]; xpreB = p[1];
      }
    }
    __syncthreads();  // x_t, h_t visible

    f32x4 acc[4];
    #pragma unroll
    for (int i=0;i<4;i++) acc[i] = (f32x4){0.f,0.f,0.f,0.f};
    #pragma unroll
    for (int ks=0;ks<8;ks++){
      bf8 a = *reinterpret_cast<const bf8*>(&xh[mL*264 + ks*32 + kb]);
      #pragma unroll
      for (int n=0;n<4;n++)
        acc[n] = __builtin_amdgcn_mfma_f32_16x16x32_bf16(a, Breg[n][ks], acc[n], 0,0,0);
    }
    {
      const int row0 = quad*4;
      #pragma unroll
      for (int n=0;n<4;n++){
        int col = wave*64 + n*16 + mL;
        #pragma unroll
        for (int i=0;i<4;i++)
          gates[(row0+i)*520 + col] = acc[n][i] + bias[n];
      }
    }
    __syncthreads();  // gates visible

    {
      const float* g = &gates[eseq*520 + ech];
      f32x4 gi_ = *reinterpret_cast<const f32x4*>(g);
      f32x4 gf_ = *reinterpret_cast<const f32x4*>(g+128);
      f32x4 gg_ = *reinterpret_cast<const f32x4*>(g+256);
      f32x4 go_ = *reinterpret_cast<const f32x4*>(g+384);
      s16x4 hp;
      #pragma unroll
      for (int i=0;i<4;i++){
        float c = sigm(gf_[i])*cst[i] + sigm(gi_[i])*tanh_(gg_[i]);
        float h = sigm(go_[i])*tanh_(c);
        cst[i]=c; hst[i]=h;
        hp[i] = (short)f2bf(h);
      }
      *reinterpret_cast<s16x4*>(&xh[eseq*264 + 128 + ech]) = hp;
    }
    // loop-top barrier protects h writes vs next mfma reads
  }

  {
    int gs = s0 + eseq;
    s16x4 cp_, hp_;
    #pragma unroll
    for (int i=0;i<4;i++){ cp_[i]=(short)f2bf(cst[i]); hp_[i]=(short)f2bf(hst[i]); }
    *reinterpret_cast<s16x4*>(c_cat + gs*256 + dir*128 + ech) = cp_;
    *reinterpret_cast<s16x4*>(h_cat + gs*256 + dir*128 + ech) = hp_;
  }
}

// ---------------------------------------------------------------------------
// Stage 2: enc_states = [relu([cf|cb]@Wc.T+bc) | relu([hf|hb]@Whr.T+bhr)]
// -> hidden fp32 + bf16 mirror; row 0 zeroed.
// ---------------------------------------------------------------------------
__global__ __launch_bounds__(256) void reduce_kernel(
    const u16* __restrict__ c_cat, const u16* __restrict__ h_cat,
    const u16* __restrict__ Wc, const float* __restrict__ bc,
    const u16* __restrict__ Whr, const float* __restrict__ bhr,
    float* __restrict__ hidf, u16* __restrict__ hidb)
{
  const int tid=threadIdx.x, wave=tid>>6, lane=tid&63;
  const int mL=lane&15, quad=lane>>4, kb=quad*8;
  const int m0 = blockIdx.x*64;
  const u16* A    = (wave<2) ? c_cat : h_cat;
  const u16* W    = (wave<2) ? Wc  : Whr;
  const float* bv = (wave<2) ? bc  : bhr;
  const int nb    = (wave&1)*64;
  const int obase = (wave<2) ? 0 : 128;

  f32x4 acc[4][4];
  #pragma unroll
  for (int mt=0;mt<4;mt++)
    #pragma unroll
    for (int nt=0;nt<4;nt++) acc[mt][nt] = (f32x4){0.f,0.f,0.f,0.f};

  #pragma unroll
  for (int ks=0;ks<8;ks++){
    int k = ks*32 + kb;
    bf8 bfr[4];
    #pragma unroll
    for (int nt=0;nt<4;nt++)
      bfr[nt] = *reinterpret_cast<const bf8*>(W + (nb+nt*16+mL)*256 + k);
    #pragma unroll
    for (int mt=0;mt<4;mt++){
      bf8 a = *reinterpret_cast<const bf8*>(A + (m0+mt*16+mL)*256 + k);
      #pragma unroll
      for (int nt=0;nt<4;nt++)
        acc[mt][nt] = __builtin_amdgcn_mfma_f32_16x16x32_bf16(a, bfr[nt], acc[mt][nt], 0,0,0);
    }
  }
  const int row0 = quad*4;
  float biasv[4];
  #pragma unroll
  for (int nt=0;nt<4;nt++) biasv[nt] = bv[nb+nt*16+mL];
  #pragma unroll
  for (int mt=0;mt<4;mt++){
    #pragma unroll
    for (int nt=0;nt<4;nt++){
      int col = obase + nb + nt*16 + mL;
      #pragma unroll
      for (int i=0;i<4;i++){
        int r = m0 + mt*16 + row0 + i;
        float v = fmaxf(acc[mt][nt][i] + biasv[nt], 0.f);
        hidf[(r+1)*256 + col] = v;
        hidb[(r+1)*256 + col] = f2bf(v);
      }
    }
  }
  if (blockIdx.x==0 && tid<64){
    #pragma unroll
    for (int j=0;j<4;j++){ hidf[tid*4+j] = 0.f; hidb[tid*4+j] = 0; }
  }
}

// ---------------------------------------------------------------------------
// Stage 3 (x4): gi = hidden@Wi.T + bi, gh = hidden@Wh.T + bh  (bf16 tables)
// ---------------------------------------------------------------------------
__global__ __launch_bounds__(256) void gates_gemm_kernel(
    const u16* __restrict__ hidb,
    const u16* __restrict__ Wi, const u16* __restrict__ Wh,
    const float* __restrict__ bi, const float* __restrict__ bh,
    u16* __restrict__ gi, u16* __restrict__ gh)
{
  const int tid=threadIdx.x, wave=tid>>6, lane=tid&63;
  const int mL=lane&15, quad=lane>>4, kb=quad*8;
  const int m0 = blockIdx.x*64;
  const int n0 = blockIdx.y*256 + wave*64;
  const bool isI = (n0 < 768);
  const u16* W    = isI ? Wi : Wh;
  const float* bv = isI ? bi : bh;
  u16* out        = isI ? gi : gh;
  const int nb    = isI ? n0 : (n0-768);

  int arow[4];
  #pragma unroll
  for (int mt=0;mt<4;mt++) arow[mt] = min(m0+mt*16+mL, NR-1);

  f32x4 acc[4][4];
  #pragma unroll
  for (int mt=0;mt<4;mt++)
    #pragma unroll
    for (int nt=0;nt<4;nt++) acc[mt][nt] = (f32x4){0.f,0.f,0.f,0.f};

  #pragma unroll
  for (int ks=0;ks<8;ks++){
    int k = ks*32 + kb;
    bf8 bfr[4];
    #pragma unroll
    for (int nt=0;nt<4;nt++)
      bfr[nt] = *reinterpret_cast<const bf8*>(W + (nb+nt*16+mL)*256 + k);
    #pragma unroll
    for (int mt=0;mt<4;mt++){
      bf8 a = *reinterpret_cast<const bf8*>(hidb + arow[mt]*256 + k);
      #pragma unroll
      for (int nt=0;nt<4;nt++)
        acc[mt][nt] = __builtin_amdgcn_mfma_f32_16x16x32_bf16(a, bfr[nt], acc[mt][nt], 0,0,0);
    }
  }
  const int row0 = quad*4;
  float biasv[4];
  #pragma unroll
  for (int nt=0;nt<4;nt++) biasv[nt] = bv[nb+nt*16+mL];
  #pragma unroll
  for (int mt=0;mt<4;mt++){
    #pragma unroll
    for (int nt=0;nt<4;nt++){
      #pragma unroll
      for (int i=0;i<4;i++){
        int r = m0 + mt*16 + row0 + i;
        if (r < NR)
          out[r*768 + nb + nt*16 + mL] = f2bf(acc[mt][nt][i] + biasv[nt]);
      }
    }
  }
}

// ---------------------------------------------------------------------------
// Stage 4 (x4): per output row, loop partners, GRU elementwise, mask-skip,
// block L2-norm -> scale, double-buffered hidden update.
// mode 0 = cp (fixed j, loop i, x=child, h=parent, sum over i)
// mode 1 = pc (fixed i, loop j, x=parent, h=child,  sum over j)
// ---------------------------------------------------------------------------
__global__ __launch_bounds__(256) void pair_kernel(
    const u16* __restrict__ gi, const u16* __restrict__ gh,
    const float* __restrict__ hin,
    float* __restrict__ hout, u16* __restrict__ bout, float* __restrict__ dout,
    const int* __restrict__ par, const int* __restrict__ chi,
    const float* __restrict__ mask, const int mode)
{
  const int r  = blockIdx.x;
  const int ch = threadIdx.x;
  __shared__ float partial[4];
  if (r==0){
    hout[ch] = 0.f; bout[ch] = 0;
    if (dout) dout[ch] = 0.f;
    return;
  }
  const int b=(r-1)/S_, fx=(r-1)%S_;
  const int base = b*S_*S_;
  float acc = 0.f;
  for (int l=0;l<S_;l++){
    int idx = mode ? (base + fx*S_ + l) : (base + l*S_ + fx);
    float m = mask[idx];
    if (m == 0.f) continue;            // wave-uniform (same for whole block)
    int p = par[idx], c = chi[idx];
    int xr = mode ? p : c;             // gi row (GRU input x)
    int hr = mode ? c : p;             // gh + hidden row (GRU state h)
    float ir  = bf2f(gi[xr*768       + ch]);
    float iz  = bf2f(gi[xr*768 + 256 + ch]);
    float inn = bf2f(gi[xr*768 + 512 + ch]);
    float r1  = bf2f(gh[hr*768       + ch]);
    float z1  = bf2f(gh[hr*768 + 256 + ch]);
    float n1  = bf2f(gh[hr*768 + 512 + ch]);
    float hv  = hin[hr*256 + ch];
    float rr = sigm(ir + r1);
    float zz = sigm(iz + z1);
    float nn = tanh_(inn + rr*n1);
    acc += m*((1.f-zz)*nn + zz*hv);
  }
  float s = acc*acc;
  #pragma unroll
  for (int off=32; off>0; off>>=1) s += __shfl_xor(s, off, 64);
  if ((ch&63)==0) partial[ch>>6] = s;
  __syncthreads();
  float v  = sqrtf(partial[0]+partial[1]+partial[2]+partial[3]);
  float sc = (v + 0.25f)/(v + 1.f);
  float nv = hin[r*256 + ch] + acc*sc;
  hout[r*256 + ch] = nv;
  bout[r*256 + ch] = f2bf(nv);
  if (dout) dout[r*256 + ch] = nv;
}

// ---------------------------------------------------------------------------
extern "C" void kernel_launch(void* const* d_in, const int* in_sizes, int n_in,
                              void* d_out, int out_size, void* d_ws, size_t ws_size,
                              hipStream_t stream)
{
  const int*   enc  = (const int*)  d_in[0];
  const int*   spar = (const int*)  d_in[1];
  const int*   schi = (const int*)  d_in[2];
  const float* mask = (const float*)d_in[3];
  const float* emb  = (const float*)d_in[4];
  const float* WihF = (const float*)d_in[5];
  const float* WhhF = (const float*)d_in[6];
  const float* bF   = (const float*)d_in[7];
  const float* WihB = (const float*)d_in[8];
  const float* WhhB = (const float*)d_in[9];
  const float* bB   = (const float*)d_in[10];
  const float* Wc   = (const float*)d_in[11];
  const float* bc   = (const float*)d_in[12];
  const float* Whr  = (const float*)d_in[13];
  const float* bhr  = (const float*)d_in[14];
  const float* WiCP = (const float*)d_in[15];
  const float* WhCP = (const float*)d_in[16];
  const float* biCP = (const float*)d_in[17];
  const float* bhCP = (const float*)d_in[18];
  const float* WiPC = (const float*)d_in[19];
  const float* WhPC = (const float*)d_in[20];
  const float* biPC = (const float*)d_in[21];
  const float* bhPC = (const float*)d_in[22];

  // workspace layout (~12.6 MB total)
  char* ws = (char*)d_ws;
  u16*   c_cat = (u16*)  (ws + 0);         // 1536*256 bf16
  u16*   h_cat = (u16*)  (ws + 786432);    // 1536*256 bf16
  float* hf0   = (float*)(ws + 1572864);   // 1537*256 f32
  float* hf1   = (float*)(ws + 3146752);
  u16*   hb0   = (u16*)  (ws + 4720640);   // 1537*256 bf16
  u16*   hb1   = (u16*)  (ws + 5507584);
  u16*   gi    = (u16*)  (ws + 6294528);   // 1537*768 bf16
  u16*   gh    = (u16*)  (ws + 8655360);   // 1537*768 bf16
  u16*   wbf   = (u16*)  (ws + 11016192);  // bf16 weight copies (1114112 elems)
  float* out   = (float*)d_out;

  // bf16 weight copy offsets (elements)
  u16* bWihF = wbf + 0;
  u16* bWhhF = wbf + 65536;
  u16* bWihB = wbf + 131072;
  u16* bWhhB = wbf + 196608;
  u16* bWc   = wbf + 262144;
  u16* bWhr  = wbf + 294912;
  u16* bWiCP = wbf + 327680;
  u16* bWhCP = wbf + 524288;
  u16* bWiPC = wbf + 720896;
  u16* bWhPC = wbf + 917504;

  CvtArgs ca;
  ca.s[0]=WihF; ca.s[1]=WhhF; ca.s[2]=WihB; ca.s[3]=WhhB;
  ca.s[4]=Wc;   ca.s[5]=Whr;
  ca.s[6]=WiCP; ca.s[7]=WhCP; ca.s[8]=WiPC; ca.s[9]=WhPC;
  ca.d[0]=bWihF; ca.d[1]=bWhhF; ca.d[2]=bWihB; ca.d[3]=bWhhB;
  ca.d[4]=bWc;   ca.d[5]=bWhr;
  ca.d[6]=bWiCP; ca.d[7]=bWhCP; ca.d[8]=bWiPC; ca.d[9]=bWhPC;
  cvt_kernel<<<dim3(1088), dim3(256), 0, stream>>>(ca);

  lstm_kernel<<<dim3(96,2), dim3(512), 0, stream>>>(
      enc, emb, bWihF,bWhhF,bF, bWihB,bWhhB,bB, c_cat, h_cat);
  reduce_kernel<<<dim3(24), dim3(256), 0, stream>>>(
      c_cat,h_cat, bWc,bc,bWhr,bhr, hf0,hb0);

  float* hfb[2] = {hf0,hf1};
  u16*   hbb[2] = {hb0,hb1};
  int cur = 0;
  for (int it=0; it<4; it++){
    const u16* Wi   = (it<2)?bWiCP:bWiPC;
    const u16* Wh   = (it<2)?bWhCP:bWhPC;
    const float* bi = (it<2)?biCP:biPC;
    const float* bh = (it<2)?bhCP:bhPC;
    int nxt = cur^1;
    gates_gemm_kernel<<<dim3(25,6), dim3(256), 0, stream>>>(
        hbb[cur], Wi,Wh,bi,bh, gi,gh);
    pair_kernel<<<dim3(NR), dim3(256), 0, stream>>>(
        gi,gh, hfb[cur], hfb[nxt], hbb[nxt],
        (it==3)?out:(float*)nullptr, spar,schi,mask, (it<2)?0:1);
    cur = nxt;
  }
}

// Round 3
// 474.651 us; speedup vs baseline: 1.0374x; 1.0374x over previous
//
#include <hip/hip_runtime.h>

typedef unsigned short u16;
typedef __attribute__((ext_vector_type(8))) short bf8;    // 8 x bf16 MFMA fragment
typedef __attribute__((ext_vector_type(4))) short s16x4;
typedef __attribute__((ext_vector_type(4))) float f32x4;
typedef __attribute__((ext_vector_type(4))) int   i32x4;

#define S_   96
#define T_   50
#define NSEQ 1536
#define NR   1537
// hidden width 256, gate width 768

__device__ __forceinline__ float bf2f(u16 u){ return __uint_as_float(((unsigned)u)<<16); }
__device__ __forceinline__ u16 f2bf(float f){
  unsigned u = __float_as_uint(f);
  u += 0x7fffu + ((u>>16)&1u);           // RNE
  return (u16)(u>>16);
}
__device__ __forceinline__ float sigm(float x){
  x = fminf(30.f, fmaxf(-30.f, x));
  return 1.f/(1.f+__expf(-x));
}
__device__ __forceinline__ float tanh_(float x){
  x = fminf(15.f, fmaxf(-15.f, x));
  float e = __expf(2.f*x);
  return (e-1.f)/(e+1.f);
}

// ---------------------------------------------------------------------------
// Stage 0: convert fp32 weights to bf16; LSTM weights (t<4) are row-permuted
// so that MFMA slot (wave w, n-tile n, lane mL) = gate-type n, channel w*16+mL.
// orig_row(col') = ((col'>>4)&3)*128 + ((col'>>6)<<4) + (col'&15)
// sizes: 4x(512*128) | 2x(128*256) | 4x(768*256)  = 1114112 elems
// ---------------------------------------------------------------------------
struct CvtArgs { const float* s[10]; u16* d[10]; };
__global__ __launch_bounds__(256) void cvt_kernel(CvtArgs a){
  int e = (blockIdx.x*256 + threadIdx.x)*4;
  if (e >= 1114112) return;
  int t, off;
  if (e < 262144){ t = e>>16; off = e & 65535; }
  else if (e < 327680){ int e2=e-262144; t = 4+(e2>>15); off = e2&32767; }
  else { int e3=e-327680; t = 6 + e3/196608; off = e3%196608; }
  int src = off;
  if (t < 4){
    int colp = off>>7, k = off&127;
    int orig = ((colp>>4)&3)*128 + ((colp>>6)<<4) + (colp&15);
    src = orig*128 + k;
  }
  f32x4 v = *reinterpret_cast<const f32x4*>(a.s[t]+src);
  s16x4 o;
  #pragma unroll
  for (int i=0;i<4;i++) o[i]=(short)f2bf(v[i]);
  *reinterpret_cast<s16x4*>(a.d[t]+off) = o;
}

// ---------------------------------------------------------------------------
// Stage 0b: compact active-partner lists (mask/indices are round-invariant).
// mode0 (cp): out row j=fx, partners i=l : entry (xr=chi, hr=par)
// mode1 (pc): out row i=fx, partners j=l : entry (xr=par, hr=chi)
// ---------------------------------------------------------------------------
__global__ __launch_bounds__(256) void build_lists(
    const int* __restrict__ par, const int* __restrict__ chi,
    const float* __restrict__ mask,
    int2* __restrict__ ent0, int* __restrict__ cnt0,
    int2* __restrict__ ent1, int* __restrict__ cnt1)
{
  int rr = blockIdx.x*256 + threadIdx.x;
  if (rr >= NSEQ) return;
  int b = rr/S_, fx = rr%S_, base = b*S_*S_;
  int c0=0, c1=0;
  for (int l=0;l<S_;l++){
    int idx = base + l*S_ + fx;
    if (mask[idx] != 0.f){ ent0[rr*S_ + c0] = make_int2(chi[idx], par[idx]); c0++; }
    int jdx = base + fx*S_ + l;
    if (mask[jdx] != 0.f){ ent1[rr*S_ + c1] = make_int2(par[jdx], chi[jdx]); c1++; }
  }
  cnt0[rr]=c0; cnt1[rr]=c1;
}

// ---------------------------------------------------------------------------
// Stage 1: bidirectional LSTM final states. 16 seqs/block, 8 waves, weights
// register-resident (asm-pinned). Gate-permuted weights -> all 4 gates of a
// (seq,ch) land in one lane's accumulators; cell update is pure-register.
// LDS row: [x0(128)|x1(128)|h0(128)|h1(128)|pad(8)] shorts, one barrier/step.
// ---------------------------------------------------------------------------
__global__ __launch_bounds__(512, 2) void lstm_kernel(
    const int* __restrict__ enc, const float* __restrict__ emb,
    const u16* __restrict__ WihF, const u16* __restrict__ WhhF, const float* __restrict__ bF,
    const u16* __restrict__ WihB, const u16* __restrict__ WhhB, const float* __restrict__ bB,
    u16* __restrict__ c_cat, u16* __restrict__ h_cat)
{
  __shared__ short xh[16*520];
  __shared__ int   toks[16*T_];

  const int tid  = threadIdx.x;
  const int wave = tid>>6;
  const int lane = tid&63;
  const int dir  = blockIdx.y;
  const int s0   = blockIdx.x*16;

  const u16* Wih = dir ? WihB : WihF;
  const u16* Whh = dir ? WhhB : WhhF;
  const float* bb = dir ? bB  : bF;

  for (int i=tid; i<16*T_; i+=512)
    toks[i] = enc[(s0 + i/T_)*T_ + (i%T_)];

  const int mL   = lane&15;
  const int quad = lane>>4;
  const int kb   = quad*8;

  // permuted weight fragments, pinned in VGPRs
  bf8 Breg[4][8];
  float bias[4];
  #pragma unroll
  for (int n=0;n<4;n++){
    int colp = wave*64 + n*16 + mL;
    bias[n] = bb[n*128 + wave*16 + mL];
    #pragma unroll
    for (int ks=0;ks<8;ks++){
      int k = ks*32 + kb;
      const u16* p = (k<128) ? (Wih + colp*128 + k) : (Whh + colp*128 + (k-128));
      Breg[n][ks] = *reinterpret_cast<const bf8*>(p);
      asm volatile("" : "+v"(Breg[n][ks]));
    }
  }

  // zero h0 region
  if (tid<256){
    int r = tid>>4, c = tid&15;
    *reinterpret_cast<i32x4*>(&xh[r*520 + 256 + c*8]) = (i32x4){0,0,0,0};
  }

  const int srow = tid>>5, schunk = tid&31;   // staging map (all 512 threads)
  float cst[4] = {0.f,0.f,0.f,0.f};
  float hst[4] = {0.f,0.f,0.f,0.f};

  __syncthreads();  // toks + zero-h0 visible

  { // stage x[0]
    int tt0 = dir ? (T_-1) : 0;
    int tok = toks[srow*T_ + tt0];
    f32x4 xv = *reinterpret_cast<const f32x4*>(emb + tok*128 + schunk*4);
    s16x4 xp;
    #pragma unroll
    for (int i=0;i<4;i++) xp[i]=(short)f2bf(xv[i]);
    *reinterpret_cast<s16x4*>(&xh[srow*520 + schunk*4]) = xp;
  }
  __syncthreads();

  for (int t=0;t<T_;t++){
    const int cb = t&1, nb = (t+1)&1;
    // issue stage loads for t+1 early (overlap with MFMA)
    f32x4 xv; bool have = (t+1 < T_);
    if (have){
      int tt = dir ? (T_-2-t) : (t+1);
      int tok = toks[srow*T_ + tt];
      xv = *reinterpret_cast<const f32x4*>(emb + tok*128 + schunk*4);
    }

    f32x4 acc[4];
    #pragma unroll
    for (int i=0;i<4;i++) acc[i] = (f32x4){0.f,0.f,0.f,0.f};
    #pragma unroll
    for (int ks=0;ks<8;ks++){
      int k = ks*32 + kb;
      int off = (k<128) ? (cb*128 + k) : (256 + cb*128 + (k-128));
      bf8 a = *reinterpret_cast<const bf8*>(&xh[mL*520 + off]);
      #pragma unroll
      for (int n=0;n<4;n++)
        acc[n] = __builtin_amdgcn_mfma_f32_16x16x32_bf16(a, Breg[n][ks], acc[n], 0,0,0);
    }

    if (have){
      s16x4 xp;
      #pragma unroll
      for (int i=0;i<4;i++) xp[i]=(short)f2bf(xv[i]);
      *reinterpret_cast<s16x4*>(&xh[srow*520 + nb*128 + schunk*4]) = xp;
    }

    // cell update in registers; h -> LDS h[nb]
    #pragma unroll
    for (int i=0;i<4;i++){
      float gi_ = acc[0][i]+bias[0];
      float gf_ = acc[1][i]+bias[1];
      float gg_ = acc[2][i]+bias[2];
      float go_ = acc[3][i]+bias[3];
      float c = sigm(gf_)*cst[i] + sigm(gi_)*tanh_(gg_);
      float h = sigm(go_)*tanh_(c);
      cst[i]=c; hst[i]=h;
      xh[(quad*4+i)*520 + 256 + nb*128 + wave*16 + mL] = (short)f2bf(h);
    }
    __syncthreads();
  }

  {
    const int ch = wave*16 + mL;
    #pragma unroll
    for (int i=0;i<4;i++){
      int gs = s0 + quad*4 + i;
      c_cat[gs*256 + dir*128 + ch] = f2bf(cst[i]);
      h_cat[gs*256 + dir*128 + ch] = f2bf(hst[i]);
    }
  }
}

// ---------------------------------------------------------------------------
// Stage 2: enc_states = [relu([cf|cb]@Wc.T+bc) | relu([hf|hb]@Whr.T+bhr)]
// -> hidden fp32 + bf16 mirror; row 0 zeroed.
// ---------------------------------------------------------------------------
__global__ __launch_bounds__(256) void reduce_kernel(
    const u16* __restrict__ c_cat, const u16* __restrict__ h_cat,
    const u16* __restrict__ Wc, const float* __restrict__ bc,
    const u16* __restrict__ Whr, const float* __restrict__ bhr,
    float* __restrict__ hidf, u16* __restrict__ hidb)
{
  const int tid=threadIdx.x, wave=tid>>6, lane=tid&63;
  const int mL=lane&15, quad=lane>>4, kb=quad*8;
  const int m0 = blockIdx.x*64;
  const u16* A    = (wave<2) ? c_cat : h_cat;
  const u16* W    = (wave<2) ? Wc  : Whr;
  const float* bv = (wave<2) ? bc  : bhr;
  const int nb    = (wave&1)*64;
  const int obase = (wave<2) ? 0 : 128;

  f32x4 acc[4][4];
  #pragma unroll
  for (int mt=0;mt<4;mt++)
    #pragma unroll
    for (int nt=0;nt<4;nt++) acc[mt][nt] = (f32x4){0.f,0.f,0.f,0.f};

  #pragma unroll
  for (int ks=0;ks<8;ks++){
    int k = ks*32 + kb;
    bf8 bfr[4];
    #pragma unroll
    for (int nt=0;nt<4;nt++)
      bfr[nt] = *reinterpret_cast<const bf8*>(W + (nb+nt*16+mL)*256 + k);
    #pragma unroll
    for (int mt=0;mt<4;mt++){
      bf8 a = *reinterpret_cast<const bf8*>(A + (m0+mt*16+mL)*256 + k);
      #pragma unroll
      for (int nt=0;nt<4;nt++)
        acc[mt][nt] = __builtin_amdgcn_mfma_f32_16x16x32_bf16(a, bfr[nt], acc[mt][nt], 0,0,0);
    }
  }
  const int row0 = quad*4;
  float biasv[4];
  #pragma unroll
  for (int nt=0;nt<4;nt++) biasv[nt] = bv[nb+nt*16+mL];
  #pragma unroll
  for (int mt=0;mt<4;mt++){
    #pragma unroll
    for (int nt=0;nt<4;nt++){
      int col = obase + nb + nt*16 + mL;
      #pragma unroll
      for (int i=0;i<4;i++){
        int r = m0 + mt*16 + row0 + i;
        float v = fmaxf(acc[mt][nt][i] + biasv[nt], 0.f);
        hidf[(r+1)*256 + col] = v;
        hidb[(r+1)*256 + col] = f2bf(v);
      }
    }
  }
  if (blockIdx.x==0 && tid<64){
    #pragma unroll
    for (int j=0;j<4;j++){ hidf[tid*4+j] = 0.f; hidb[tid*4+j] = 0; }
  }
}

// ---------------------------------------------------------------------------
// Stage 3 (x4): gi = hidden@Wi.T + bi, gh = hidden@Wh.T + bh  (bf16 tables)
// M-tile 32 -> 294 blocks for latency hiding.
// ---------------------------------------------------------------------------
__global__ __launch_bounds__(256) void gates_gemm_kernel(
    const u16* __restrict__ hidb,
    const u16* __restrict__ Wi, const u16* __restrict__ Wh,
    const float* __restrict__ bi, const float* __restrict__ bh,
    u16* __restrict__ gi, u16* __restrict__ gh)
{
  const int tid=threadIdx.x, wave=tid>>6, lane=tid&63;
  const int mL=lane&15, quad=lane>>4, kb=quad*8;
  const int m0 = blockIdx.x*32;
  const int n0 = blockIdx.y*256 + wave*64;
  const bool isI = (n0 < 768);
  const u16* W    = isI ? Wi : Wh;
  const float* bv = isI ? bi : bh;
  u16* out        = isI ? gi : gh;
  const int nbc   = isI ? n0 : (n0-768);

  int arow[2];
  #pragma unroll
  for (int mt=0;mt<2;mt++) arow[mt] = min(m0+mt*16+mL, NR-1);

  f32x4 acc[2][4];
  #pragma unroll
  for (int mt=0;mt<2;mt++)
    #pragma unroll
    for (int nt=0;nt<4;nt++) acc[mt][nt] = (f32x4){0.f,0.f,0.f,0.f};

  #pragma unroll
  for (int ks=0;ks<8;ks++){
    int k = ks*32 + kb;
    bf8 bfr[4];
    #pragma unroll
    for (int nt=0;nt<4;nt++)
      bfr[nt] = *reinterpret_cast<const bf8*>(W + (nbc+nt*16+mL)*256 + k);
    #pragma unroll
    for (int mt=0;mt<2;mt++){
      bf8 a = *reinterpret_cast<const bf8*>(hidb + arow[mt]*256 + k);
      #pragma unroll
      for (int nt=0;nt<4;nt++)
        acc[mt][nt] = __builtin_amdgcn_mfma_f32_16x16x32_bf16(a, bfr[nt], acc[mt][nt], 0,0,0);
    }
  }
  const int row0 = quad*4;
  float biasv[4];
  #pragma unroll
  for (int nt=0;nt<4;nt++) biasv[nt] = bv[nbc+nt*16+mL];
  #pragma unroll
  for (int mt=0;mt<2;mt++){
    #pragma unroll
    for (int nt=0;nt<4;nt++){
      #pragma unroll
      for (int i=0;i<4;i++){
        int r = m0 + mt*16 + row0 + i;
        if (r < NR)
          out[r*768 + nbc + nt*16 + mL] = f2bf(acc[mt][nt][i] + biasv[nt]);
      }
    }
  }
}

// ---------------------------------------------------------------------------
// Stage 4 (x4): block per output row; active partners split across 4 waves
// (compacted lists, branch-free); GRU elementwise fp32; LDS cross-wave sum;
// L2-norm scale; double-buffered hidden update.
// ---------------------------------------------------------------------------
__global__ __launch_bounds__(256) void pair_kernel(
    const u16* __restrict__ gi, const u16* __restrict__ gh,
    const float* __restrict__ hin,
    float* __restrict__ hout, u16* __restrict__ bout, float* __restrict__ dout,
    const int2* __restrict__ ent, const int* __restrict__ cnt)
{
  const int r = blockIdx.x;
  const int tid = threadIdx.x, wave = tid>>6, lane = tid&63;
  __shared__ float part[4][260];
  __shared__ float ssum[4];
  if (r==0){
    hout[tid]=0.f; bout[tid]=0;
    if (dout) dout[tid]=0.f;
    return;
  }
  const int rr = r-1;
  const int n  = cnt[rr];
  const int2* e = ent + rr*S_;
  const int ch0 = lane*4;

  float a0=0.f, a1=0.f, a2=0.f, a3=0.f;
  for (int k=wave; k<n; k+=4){
    int2 pr = e[k];
    const u16* gx = gi + pr.x*768 + ch0;
    const u16* gy = gh + pr.y*768 + ch0;
    s16x4 vi0 = *reinterpret_cast<const s16x4*>(gx);
    s16x4 vi1 = *reinterpret_cast<const s16x4*>(gx+256);
    s16x4 vi2 = *reinterpret_cast<const s16x4*>(gx+512);
    s16x4 vh0 = *reinterpret_cast<const s16x4*>(gy);
    s16x4 vh1 = *reinterpret_cast<const s16x4*>(gy+256);
    s16x4 vh2 = *reinterpret_cast<const s16x4*>(gy+512);
    f32x4 hv  = *reinterpret_cast<const f32x4*>(hin + pr.y*256 + ch0);
    float o[4];
    #pragma unroll
    for (int i=0;i<4;i++){
      float rg = sigm(bf2f((u16)vi0[i]) + bf2f((u16)vh0[i]));
      float zg = sigm(bf2f((u16)vi1[i]) + bf2f((u16)vh1[i]));
      float ng = tanh_(bf2f((u16)vi2[i]) + rg*bf2f((u16)vh2[i]));
      o[i] = (1.f-zg)*ng + zg*hv[i];
    }
    a0 += o[0]; a1 += o[1]; a2 += o[2]; a3 += o[3];
  }
  *reinterpret_cast<f32x4*>(&part[wave][ch0]) = (f32x4){a0,a1,a2,a3};
  __syncthreads();

  float tot = part[0][tid] + part[1][tid] + part[2][tid] + part[3][tid];
  float sq = tot*tot;
  #pragma unroll
  for (int off=32; off>0; off>>=1) sq += __shfl_xor(sq, off, 64);
  if (lane==0) ssum[wave] = sq;
  __syncthreads();
  float v  = sqrtf(ssum[0]+ssum[1]+ssum[2]+ssum[3]);
  float sc = (v + 0.25f)/(v + 1.f);
  float nv = hin[r*256 + tid] + tot*sc;
  hout[r*256 + tid] = nv;
  bout[r*256 + tid] = f2bf(nv);
  if (dout) dout[r*256 + tid] = nv;
}

// ---------------------------------------------------------------------------
extern "C" void kernel_launch(void* const* d_in, const int* in_sizes, int n_in,
                              void* d_out, int out_size, void* d_ws, size_t ws_size,
                              hipStream_t stream)
{
  const int*   enc  = (const int*)  d_in[0];
  const int*   spar = (const int*)  d_in[1];
  const int*   schi = (const int*)  d_in[2];
  const float* mask = (const float*)d_in[3];
  const float* emb  = (const float*)d_in[4];
  const float* WihF = (const float*)d_in[5];
  const float* WhhF = (const float*)d_in[6];
  const float* bF   = (const float*)d_in[7];
  const float* WihB = (const float*)d_in[8];
  const float* WhhB = (const float*)d_in[9];
  const float* bB   = (const float*)d_in[10];
  const float* Wc   = (const float*)d_in[11];
  const float* bc   = (const float*)d_in[12];
  const float* Whr  = (const float*)d_in[13];
  const float* bhr  = (const float*)d_in[14];
  const float* WiCP = (const float*)d_in[15];
  const float* WhCP = (const float*)d_in[16];
  const float* biCP = (const float*)d_in[17];
  const float* bhCP = (const float*)d_in[18];
  const float* WiPC = (const float*)d_in[19];
  const float* WhPC = (const float*)d_in[20];
  const float* biPC = (const float*)d_in[21];
  const float* bhPC = (const float*)d_in[22];

  // workspace layout (~14.8 MB)
  char* ws = (char*)d_ws;
  u16*   c_cat = (u16*)  (ws + 0);          // 1536*256 bf16
  u16*   h_cat = (u16*)  (ws + 786432);
  float* hf0   = (float*)(ws + 1572864);    // 1537*256 f32
  float* hf1   = (float*)(ws + 3146752);
  u16*   hb    = (u16*)  (ws + 4720640);    // 1537*256 bf16 (single buffer)
  u16*   gi    = (u16*)  (ws + 5507584);    // 1537*768 bf16
  u16*   gh    = (u16*)  (ws + 7868416);
  u16*   wbf   = (u16*)  (ws + 10229248);   // bf16 weights (1114112 elems)
  int2*  ent0  = (int2*) (ws + 12457472);   // 1536*96 int2
  int2*  ent1  = (int2*) (ws + 13637120);
  int*   cnt0  = (int*)  (ws + 14816768);
  int*   cnt1  = (int*)  (ws + 14822912);
  float* out   = (float*)d_out;

  u16* bWihF = wbf + 0;
  u16* bWhhF = wbf + 65536;
  u16* bWihB = wbf + 131072;
  u16* bWhhB = wbf + 196608;
  u16* bWc   = wbf + 262144;
  u16* bWhr  = wbf + 294912;
  u16* bWiCP = wbf + 327680;
  u16* bWhCP = wbf + 524288;
  u16* bWiPC = wbf + 720896;
  u16* bWhPC = wbf + 917504;

  CvtArgs ca;
  ca.s[0]=WihF; ca.s[1]=WhhF; ca.s[2]=WihB; ca.s[3]=WhhB;
  ca.s[4]=Wc;   ca.s[5]=Whr;
  ca.s[6]=WiCP; ca.s[7]=WhCP; ca.s[8]=WiPC; ca.s[9]=WhPC;
  ca.d[0]=bWihF; ca.d[1]=bWhhF; ca.d[2]=bWihB; ca.d[3]=bWhhB;
  ca.d[4]=bWc;   ca.d[5]=bWhr;
  ca.d[6]=bWiCP; ca.d[7]=bWhCP; ca.d[8]=bWiPC; ca.d[9]=bWhPC;
  cvt_kernel<<<dim3(1088), dim3(256), 0, stream>>>(ca);
  build_lists<<<dim3(6), dim3(256), 0, stream>>>(spar, schi, mask, ent0, cnt0, ent1, cnt1);

  lstm_kernel<<<dim3(96,2), dim3(512), 0, stream>>>(
      enc, emb, bWihF,bWhhF,bF, bWihB,bWhhB,bB, c_cat, h_cat);
  reduce_kernel<<<dim3(24), dim3(256), 0, stream>>>(
      c_cat,h_cat, bWc,bc,bWhr,bhr, hf0,hb);

  float* hfb[2] = {hf0,hf1};
  int cur = 0;
  for (int it=0; it<4; it++){
    const u16* Wi   = (it<2)?bWiCP:bWiPC;
    const u16* Wh   = (it<2)?bWhCP:bWhPC;
    const float* bi = (it<2)?biCP:biPC;
    const float* bh = (it<2)?bhCP:bhPC;
    int nxt = cur^1;
    gates_gemm_kernel<<<dim3(49,6), dim3(256), 0, stream>>>(
        hb, Wi,Wh,bi,bh, gi,gh);
    pair_kernel<<<dim3(NR), dim3(256), 0, stream>>>(
        gi,gh, hfb[cur], hfb[nxt], hb,
        (it==3)?out:(float*)nullptr,
        (it<2)?ent0:ent1, (it<2)?cnt0:cnt1);
    cur = nxt;
  }
}

// Round 4
// 383.081 us; speedup vs baseline: 1.2854x; 1.2390x over previous
//
#include <hip/hip_runtime.h>

typedef unsigned short u16;
typedef __attribute__((ext_vector_type(8))) short bf8;    // 8 x bf16 MFMA fragment
typedef __attribute__((ext_vector_type(4))) short s16x4;
typedef __attribute__((ext_vector_type(4))) float f32x4;
typedef __attribute__((ext_vector_type(4))) int   i32x4;

#define S_   96
#define T_   50
#define NSEQ 1536
#define NR   1537
// hidden width 256, gate width 768

__device__ __forceinline__ float bf2f(u16 u){ return __uint_as_float(((unsigned)u)<<16); }
__device__ __forceinline__ u16 f2bf(float f){
  unsigned u = __float_as_uint(f);
  u += 0x7fffu + ((u>>16)&1u);           // RNE
  return (u16)(u>>16);
}
__device__ __forceinline__ float sigm(float x){
  x = fminf(30.f, fmaxf(-30.f, x));
  return 1.f/(1.f+__expf(-x));
}
__device__ __forceinline__ float tanh_(float x){
  x = fminf(15.f, fmaxf(-15.f, x));
  float e = __expf(2.f*x);
  return (e-1.f)/(e+1.f);
}

// ---------------------------------------------------------------------------
// Stage 0: convert fp32 weights to bf16; LSTM weights (t<4) are row-permuted
// so that MFMA slot (wave w, n-tile n, lane mL) = gate-type n, channel w*16+mL.
// orig_row(col') = ((col'>>4)&3)*128 + ((col'>>6)<<4) + (col'&15)
// sizes: 4x(512*128) | 2x(128*256) | 4x(768*256)  = 1114112 elems
// ---------------------------------------------------------------------------
struct CvtArgs { const float* s[10]; u16* d[10]; };
__global__ __launch_bounds__(256) void cvt_kernel(CvtArgs a){
  int e = (blockIdx.x*256 + threadIdx.x)*4;
  if (e >= 1114112) return;
  int t, off;
  if (e < 262144){ t = e>>16; off = e & 65535; }
  else if (e < 327680){ int e2=e-262144; t = 4+(e2>>15); off = e2&32767; }
  else { int e3=e-327680; t = 6 + e3/196608; off = e3%196608; }
  int src = off;
  if (t < 4){
    int colp = off>>7, k = off&127;
    int orig = ((colp>>4)&3)*128 + ((colp>>6)<<4) + (colp&15);
    src = orig*128 + k;
  }
  f32x4 v = *reinterpret_cast<const f32x4*>(a.s[t]+src);
  s16x4 o;
  #pragma unroll
  for (int i=0;i<4;i++) o[i]=(short)f2bf(v[i]);
  *reinterpret_cast<s16x4*>(a.d[t]+off) = o;
}

// ---------------------------------------------------------------------------
// Stage 0b: compact active-partner lists (mask/indices are round-invariant).
// One block per row; lane l tests mask element l for both modes; slot claimed
// via LDS atomic (list order arbitrary — pair sum is commutative, fp32
// reorder noise is far below the absmax threshold).
// mode0 (cp): out row j=fx, partners i=l : entry (xr=chi, hr=par)
// mode1 (pc): out row i=fx, partners j=l : entry (xr=par, hr=chi)
// ---------------------------------------------------------------------------
__global__ __launch_bounds__(128) void build_lists(
    const int* __restrict__ par, const int* __restrict__ chi,
    const float* __restrict__ mask,
    int2* __restrict__ ent0, int* __restrict__ cnt0,
    int2* __restrict__ ent1, int* __restrict__ cnt1)
{
  const int rr = blockIdx.x;
  __shared__ int c0s, c1s;
  if (threadIdx.x==0){ c0s=0; c1s=0; }
  __syncthreads();
  const int l = threadIdx.x;
  if (l < S_){
    const int b = rr/S_, fx = rr%S_, base = b*S_*S_;
    int idx = base + l*S_ + fx;
    if (mask[idx] != 0.f){
      int p = atomicAdd(&c0s, 1);
      ent0[rr*S_ + p] = make_int2(chi[idx], par[idx]);
    }
    int jdx = base + fx*S_ + l;
    if (mask[jdx] != 0.f){
      int p = atomicAdd(&c1s, 1);
      ent1[rr*S_ + p] = make_int2(par[jdx], chi[jdx]);
    }
  }
  __syncthreads();
  if (threadIdx.x==0){ cnt0[rr]=c0s; cnt1[rr]=c1s; }
}

// ---------------------------------------------------------------------------
// Stage 1: bidirectional LSTM final states. 16 seqs/block, 8 waves, weights
// register-resident (asm-pinned). Gate-permuted weights -> all 4 gates of a
// (seq,ch) land in one lane's accumulators; cell update is pure-register.
// LDS row: [x0(128)|x1(128)|h0(128)|h1(128)|pad(8)] shorts, one barrier/step.
// ---------------------------------------------------------------------------
__global__ __launch_bounds__(512, 2) void lstm_kernel(
    const int* __restrict__ enc, const float* __restrict__ emb,
    const u16* __restrict__ WihF, const u16* __restrict__ WhhF, const float* __restrict__ bF,
    const u16* __restrict__ WihB, const u16* __restrict__ WhhB, const float* __restrict__ bB,
    u16* __restrict__ c_cat, u16* __restrict__ h_cat)
{
  __shared__ short xh[16*520];
  __shared__ int   toks[16*T_];

  const int tid  = threadIdx.x;
  const int wave = tid>>6;
  const int lane = tid&63;
  const int dir  = blockIdx.y;
  const int s0   = blockIdx.x*16;

  const u16* Wih = dir ? WihB : WihF;
  const u16* Whh = dir ? WhhB : WhhF;
  const float* bb = dir ? bB  : bF;

  for (int i=tid; i<16*T_; i+=512)
    toks[i] = enc[(s0 + i/T_)*T_ + (i%T_)];

  const int mL   = lane&15;
  const int quad = lane>>4;
  const int kb   = quad*8;

  // permuted weight fragments, pinned in VGPRs
  bf8 Breg[4][8];
  float bias[4];
  #pragma unroll
  for (int n=0;n<4;n++){
    int colp = wave*64 + n*16 + mL;
    bias[n] = bb[n*128 + wave*16 + mL];
    #pragma unroll
    for (int ks=0;ks<8;ks++){
      int k = ks*32 + kb;
      const u16* p = (k<128) ? (Wih + colp*128 + k) : (Whh + colp*128 + (k-128));
      Breg[n][ks] = *reinterpret_cast<const bf8*>(p);
      asm volatile("" : "+v"(Breg[n][ks]));
    }
  }

  // zero h0 region
  if (tid<256){
    int r = tid>>4, c = tid&15;
    *reinterpret_cast<i32x4*>(&xh[r*520 + 256 + c*8]) = (i32x4){0,0,0,0};
  }

  const int srow = tid>>5, schunk = tid&31;   // staging map (all 512 threads)
  float cst[4] = {0.f,0.f,0.f,0.f};
  float hst[4] = {0.f,0.f,0.f,0.f};

  __syncthreads();  // toks + zero-h0 visible

  { // stage x[0]
    int tt0 = dir ? (T_-1) : 0;
    int tok = toks[srow*T_ + tt0];
    f32x4 xv = *reinterpret_cast<const f32x4*>(emb + tok*128 + schunk*4);
    s16x4 xp;
    #pragma unroll
    for (int i=0;i<4;i++) xp[i]=(short)f2bf(xv[i]);
    *reinterpret_cast<s16x4*>(&xh[srow*520 + schunk*4]) = xp;
  }
  __syncthreads();

  for (int t=0;t<T_;t++){
    const int cb = t&1, nb = (t+1)&1;
    // issue stage loads for t+1 early (overlap with MFMA)
    f32x4 xv; bool have = (t+1 < T_);
    if (have){
      int tt = dir ? (T_-2-t) : (t+1);
      int tok = toks[srow*T_ + tt];
      xv = *reinterpret_cast<const f32x4*>(emb + tok*128 + schunk*4);
    }

    f32x4 acc[4];
    #pragma unroll
    for (int i=0;i<4;i++) acc[i] = (f32x4){0.f,0.f,0.f,0.f};
    #pragma unroll
    for (int ks=0;ks<8;ks++){
      int k = ks*32 + kb;
      int off = (k<128) ? (cb*128 + k) : (256 + cb*128 + (k-128));
      bf8 a = *reinterpret_cast<const bf8*>(&xh[mL*520 + off]);
      #pragma unroll
      for (int n=0;n<4;n++)
        acc[n] = __builtin_amdgcn_mfma_f32_16x16x32_bf16(a, Breg[n][ks], acc[n], 0,0,0);
    }

    if (have){
      s16x4 xp;
      #pragma unroll
      for (int i=0;i<4;i++) xp[i]=(short)f2bf(xv[i]);
      *reinterpret_cast<s16x4*>(&xh[srow*520 + nb*128 + schunk*4]) = xp;
    }

    // cell update in registers; h -> LDS h[nb]
    #pragma unroll
    for (int i=0;i<4;i++){
      float gi_ = acc[0][i]+bias[0];
      float gf_ = acc[1][i]+bias[1];
      float gg_ = acc[2][i]+bias[2];
      float go_ = acc[3][i]+bias[3];
      float c = sigm(gf_)*cst[i] + sigm(gi_)*tanh_(gg_);
      float h = sigm(go_)*tanh_(c);
      cst[i]=c; hst[i]=h;
      xh[(quad*4+i)*520 + 256 + nb*128 + wave*16 + mL] = (short)f2bf(h);
    }
    __syncthreads();
  }

  {
    const int ch = wave*16 + mL;
    #pragma unroll
    for (int i=0;i<4;i++){
      int gs = s0 + quad*4 + i;
      c_cat[gs*256 + dir*128 + ch] = f2bf(cst[i]);
      h_cat[gs*256 + dir*128 + ch] = f2bf(hst[i]);
    }
  }
}

// ---------------------------------------------------------------------------
// Stage 2: enc_states = [relu([cf|cb]@Wc.T+bc) | relu([hf|hb]@Whr.T+bhr)]
// -> hidden fp32 + bf16 mirror; row 0 zeroed.
// ---------------------------------------------------------------------------
__global__ __launch_bounds__(256) void reduce_kernel(
    const u16* __restrict__ c_cat, const u16* __restrict__ h_cat,
    const u16* __restrict__ Wc, const float* __restrict__ bc,
    const u16* __restrict__ Whr, const float* __restrict__ bhr,
    float* __restrict__ hidf, u16* __restrict__ hidb)
{
  const int tid=threadIdx.x, wave=tid>>6, lane=tid&63;
  const int mL=lane&15, quad=lane>>4, kb=quad*8;
  const int m0 = blockIdx.x*64;
  const u16* A    = (wave<2) ? c_cat : h_cat;
  const u16* W    = (wave<2) ? Wc  : Whr;
  const float* bv = (wave<2) ? bc  : bhr;
  const int nb    = (wave&1)*64;
  const int obase = (wave<2) ? 0 : 128;

  f32x4 acc[4][4];
  #pragma unroll
  for (int mt=0;mt<4;mt++)
    #pragma unroll
    for (int nt=0;nt<4;nt++) acc[mt][nt] = (f32x4){0.f,0.f,0.f,0.f};

  #pragma unroll
  for (int ks=0;ks<8;ks++){
    int k = ks*32 + kb;
    bf8 bfr[4];
    #pragma unroll
    for (int nt=0;nt<4;nt++)
      bfr[nt] = *reinterpret_cast<const bf8*>(W + (nb+nt*16+mL)*256 + k);
    #pragma unroll
    for (int mt=0;mt<4;mt++){
      bf8 a = *reinterpret_cast<const bf8*>(A + (m0+mt*16+mL)*256 + k);
      #pragma unroll
      for (int nt=0;nt<4;nt++)
        acc[mt][nt] = __builtin_amdgcn_mfma_f32_16x16x32_bf16(a, bfr[nt], acc[mt][nt], 0,0,0);
    }
  }
  const int row0 = quad*4;
  float biasv[4];
  #pragma unroll
  for (int nt=0;nt<4;nt++) biasv[nt] = bv[nb+nt*16+mL];
  #pragma unroll
  for (int mt=0;mt<4;mt++){
    #pragma unroll
    for (int nt=0;nt<4;nt++){
      int col = obase + nb + nt*16 + mL;
      #pragma unroll
      for (int i=0;i<4;i++){
        int r = m0 + mt*16 + row0 + i;
        float v = fmaxf(acc[mt][nt][i] + biasv[nt], 0.f);
        hidf[(r+1)*256 + col] = v;
        hidb[(r+1)*256 + col] = f2bf(v);
      }
    }
  }
  if (blockIdx.x==0 && tid<64){
    #pragma unroll
    for (int j=0;j<4;j++){ hidf[tid*4+j] = 0.f; hidb[tid*4+j] = 0; }
  }
}

// ---------------------------------------------------------------------------
// Stage 3 (x4): gi = hidden@Wi.T + bi, gh = hidden@Wh.T + bh  (bf16 tables)
// M-tile 32 -> 294 blocks for latency hiding.
// ---------------------------------------------------------------------------
__global__ __launch_bounds__(256) void gates_gemm_kernel(
    const u16* __restrict__ hidb,
    const u16* __restrict__ Wi, const u16* __restrict__ Wh,
    const float* __restrict__ bi, const float* __restrict__ bh,
    u16* __restrict__ gi, u16* __restrict__ gh)
{
  const int tid=threadIdx.x, wave=tid>>6, lane=tid&63;
  const int mL=lane&15, quad=lane>>4, kb=quad*8;
  const int m0 = blockIdx.x*32;
  const int n0 = blockIdx.y*256 + wave*64;
  const bool isI = (n0 < 768);
  const u16* W    = isI ? Wi : Wh;
  const float* bv = isI ? bi : bh;
  u16* out        = isI ? gi : gh;
  const int nbc   = isI ? n0 : (n0-768);

  int arow[2];
  #pragma unroll
  for (int mt=0;mt<2;mt++) arow[mt] = min(m0+mt*16+mL, NR-1);

  f32x4 acc[2][4];
  #pragma unroll
  for (int mt=0;mt<2;mt++)
    #pragma unroll
    for (int nt=0;nt<4;nt++) acc[mt][nt] = (f32x4){0.f,0.f,0.f,0.f};

  #pragma unroll
  for (int ks=0;ks<8;ks++){
    int k = ks*32 + kb;
    bf8 bfr[4];
    #pragma unroll
    for (int nt=0;nt<4;nt++)
      bfr[nt] = *reinterpret_cast<const bf8*>(W + (nbc+nt*16+mL)*256 + k);
    #pragma unroll
    for (int mt=0;mt<2;mt++){
      bf8 a = *reinterpret_cast<const bf8*>(hidb + arow[mt]*256 + k);
      #pragma unroll
      for (int nt=0;nt<4;nt++)
        acc[mt][nt] = __builtin_amdgcn_mfma_f32_16x16x32_bf16(a, bfr[nt], acc[mt][nt], 0,0,0);
    }
  }
  const int row0 = quad*4;
  float biasv[4];
  #pragma unroll
  for (int nt=0;nt<4;nt++) biasv[nt] = bv[nbc+nt*16+mL];
  #pragma unroll
  for (int mt=0;mt<2;mt++){
    #pragma unroll
    for (int nt=0;nt<4;nt++){
      #pragma unroll
      for (int i=0;i<4;i++){
        int r = m0 + mt*16 + row0 + i;
        if (r < NR)
          out[r*768 + nbc + nt*16 + mL] = f2bf(acc[mt][nt][i] + biasv[nt]);
      }
    }
  }
}

// ---------------------------------------------------------------------------
// Stage 4 (x4): block per output row; active partners split across 4 waves
// (compacted lists, branch-free); GRU elementwise fp32; LDS cross-wave sum;
// L2-norm scale; double-buffered hidden update.
// ---------------------------------------------------------------------------
__global__ __launch_bounds__(256) void pair_kernel(
    const u16* __restrict__ gi, const u16* __restrict__ gh,
    const float* __restrict__ hin,
    float* __restrict__ hout, u16* __restrict__ bout, float* __restrict__ dout,
    const int2* __restrict__ ent, const int* __restrict__ cnt)
{
  const int r = blockIdx.x;
  const int tid = threadIdx.x, wave = tid>>6, lane = tid&63;
  __shared__ float part[4][260];
  __shared__ float ssum[4];
  if (r==0){
    hout[tid]=0.f; bout[tid]=0;
    if (dout) dout[tid]=0.f;
    return;
  }
  const int rr = r-1;
  const int n  = cnt[rr];
  const int2* e = ent + rr*S_;
  const int ch0 = lane*4;

  float a0=0.f, a1=0.f, a2=0.f, a3=0.f;
  for (int k=wave; k<n; k+=4){
    int2 pr = e[k];
    const u16* gx = gi + pr.x*768 + ch0;
    const u16* gy = gh + pr.y*768 + ch0;
    s16x4 vi0 = *reinterpret_cast<const s16x4*>(gx);
    s16x4 vi1 = *reinterpret_cast<const s16x4*>(gx+256);
    s16x4 vi2 = *reinterpret_cast<const s16x4*>(gx+512);
    s16x4 vh0 = *reinterpret_cast<const s16x4*>(gy);
    s16x4 vh1 = *reinterpret_cast<const s16x4*>(gy+256);
    s16x4 vh2 = *reinterpret_cast<const s16x4*>(gy+512);
    f32x4 hv  = *reinterpret_cast<const f32x4*>(hin + pr.y*256 + ch0);
    float o[4];
    #pragma unroll
    for (int i=0;i<4;i++){
      float rg = sigm(bf2f((u16)vi0[i]) + bf2f((u16)vh0[i]));
      float zg = sigm(bf2f((u16)vi1[i]) + bf2f((u16)vh1[i]));
      float ng = tanh_(bf2f((u16)vi2[i]) + rg*bf2f((u16)vh2[i]));
      o[i] = (1.f-zg)*ng + zg*hv[i];
    }
    a0 += o[0]; a1 += o[1]; a2 += o[2]; a3 += o[3];
  }
  *reinterpret_cast<f32x4*>(&part[wave][ch0]) = (f32x4){a0,a1,a2,a3};
  __syncthreads();

  float tot = part[0][tid] + part[1][tid] + part[2][tid] + part[3][tid];
  float sq = tot*tot;
  #pragma unroll
  for (int off=32; off>0; off>>=1) sq += __shfl_xor(sq, off, 64);
  if (lane==0) ssum[wave] = sq;
  __syncthreads();
  float v  = sqrtf(ssum[0]+ssum[1]+ssum[2]+ssum[3]);
  float sc = (v + 0.25f)/(v + 1.f);
  float nv = hin[r*256 + tid] + tot*sc;
  hout[r*256 + tid] = nv;
  bout[r*256 + tid] = f2bf(nv);
  if (dout) dout[r*256 + tid] = nv;
}

// ---------------------------------------------------------------------------
extern "C" void kernel_launch(void* const* d_in, const int* in_sizes, int n_in,
                              void* d_out, int out_size, void* d_ws, size_t ws_size,
                              hipStream_t stream)
{
  const int*   enc  = (const int*)  d_in[0];
  const int*   spar = (const int*)  d_in[1];
  const int*   schi = (const int*)  d_in[2];
  const float* mask = (const float*)d_in[3];
  const float* emb  = (const float*)d_in[4];
  const float* WihF = (const float*)d_in[5];
  const float* WhhF = (const float*)d_in[6];
  const float* bF   = (const float*)d_in[7];
  const float* WihB = (const float*)d_in[8];
  const float* WhhB = (const float*)d_in[9];
  const float* bB   = (const float*)d_in[10];
  const float* Wc   = (const float*)d_in[11];
  const float* bc   = (const float*)d_in[12];
  const float* Whr  = (const float*)d_in[13];
  const float* bhr  = (const float*)d_in[14];
  const float* WiCP = (const float*)d_in[15];
  const float* WhCP = (const float*)d_in[16];
  const float* biCP = (const float*)d_in[17];
  const float* bhCP = (const float*)d_in[18];
  const float* WiPC = (const float*)d_in[19];
  const float* WhPC = (const float*)d_in[20];
  const float* biPC = (const float*)d_in[21];
  const float* bhPC = (const float*)d_in[22];

  // workspace layout (~14.8 MB)
  char* ws = (char*)d_ws;
  u16*   c_cat = (u16*)  (ws + 0);          // 1536*256 bf16
  u16*   h_cat = (u16*)  (ws + 786432);
  float* hf0   = (float*)(ws + 1572864);    // 1537*256 f32
  float* hf1   = (float*)(ws + 3146752);
  u16*   hb    = (u16*)  (ws + 4720640);    // 1537*256 bf16 (single buffer)
  u16*   gi    = (u16*)  (ws + 5507584);    // 1537*768 bf16
  u16*   gh    = (u16*)  (ws + 7868416);
  u16*   wbf   = (u16*)  (ws + 10229248);   // bf16 weights (1114112 elems)
  int2*  ent0  = (int2*) (ws + 12457472);   // 1536*96 int2
  int2*  ent1  = (int2*) (ws + 13637120);
  int*   cnt0  = (int*)  (ws + 14816768);
  int*   cnt1  = (int*)  (ws + 14822912);
  float* out   = (float*)d_out;

  u16* bWihF = wbf + 0;
  u16* bWhhF = wbf + 65536;
  u16* bWihB = wbf + 131072;
  u16* bWhhB = wbf + 196608;
  u16* bWc   = wbf + 262144;
  u16* bWhr  = wbf + 294912;
  u16* bWiCP = wbf + 327680;
  u16* bWhCP = wbf + 524288;
  u16* bWiPC = wbf + 720896;
  u16* bWhPC = wbf + 917504;

  CvtArgs ca;
  ca.s[0]=WihF; ca.s[1]=WhhF; ca.s[2]=WihB; ca.s[3]=WhhB;
  ca.s[4]=Wc;   ca.s[5]=Whr;
  ca.s[6]=WiCP; ca.s[7]=WhCP; ca.s[8]=WiPC; ca.s[9]=WhPC;
  ca.d[0]=bWihF; ca.d[1]=bWhhF; ca.d[2]=bWihB; ca.d[3]=bWhhB;
  ca.d[4]=bWc;   ca.d[5]=bWhr;
  ca.d[6]=bWiCP; ca.d[7]=bWhCP; ca.d[8]=bWiPC; ca.d[9]=bWhPC;
  cvt_kernel<<<dim3(1088), dim3(256), 0, stream>>>(ca);
  build_lists<<<dim3(NSEQ), dim3(128), 0, stream>>>(spar, schi, mask, ent0, cnt0, ent1, cnt1);

  lstm_kernel<<<dim3(96,2), dim3(512), 0, stream>>>(
      enc, emb, bWihF,bWhhF,bF, bWihB,bWhhB,bB, c_cat, h_cat);
  reduce_kernel<<<dim3(24), dim3(256), 0, stream>>>(
      c_cat,h_cat, bWc,bc,bWhr,bhr, hf0,hb);

  float* hfb[2] = {hf0,hf1};
  int cur = 0;
  for (int it=0; it<4; it++){
    const u16* Wi   = (it<2)?bWiCP:bWiPC;
    const u16* Wh   = (it<2)?bWhCP:bWhPC;
    const float* bi = (it<2)?biCP:biPC;
    const float* bh = (it<2)?bhCP:bhPC;
    int nxt = cur^1;
    gates_gemm_kernel<<<dim3(49,6), dim3(256), 0, stream>>>(
        hb, Wi,Wh,bi,bh, gi,gh);
    pair_kernel<<<dim3(NR), dim3(256), 0, stream>>>(
        gi,gh, hfb[cur], hfb[nxt], hb,
        (it==3)?out:(float*)nullptr,
        (it<2)?ent0:ent1, (it<2)?cnt0:cnt1);
    cur = nxt;
  }
}

// Round 5
// 333.760 us; speedup vs baseline: 1.4754x; 1.1478x over previous
//
#include <hip/hip_runtime.h>

typedef unsigned short u16;
typedef __attribute__((ext_vector_type(8))) short bf8;    // 8 x bf16 MFMA fragment
typedef __attribute__((ext_vector_type(4))) short s16x4;
typedef __attribute__((ext_vector_type(4))) float f32x4;
typedef __attribute__((ext_vector_type(4))) int   i32x4;

#define S_   96
#define T_   50
#define NSEQ 1536
#define NR   1537
#define XROW 530   // LDS row stride in shorts (odd dword stride 265)
// hidden width 256, gate width 768

__device__ __forceinline__ float bf2f(u16 u){ return __uint_as_float(((unsigned)u)<<16); }
__device__ __forceinline__ u16 f2bf(float f){
  unsigned u = __float_as_uint(f);
  u += 0x7fffu + ((u>>16)&1u);           // RNE
  return (u16)(u>>16);
}
// division-free: rcp is 1-ulp-ish, fine vs 2% threshold. NaN-safe at +-inf.
__device__ __forceinline__ float sigm(float x){
  return __builtin_amdgcn_rcpf(1.f + __expf(-x));
}
__device__ __forceinline__ float tanh_(float x){
  return 1.f - 2.f*__builtin_amdgcn_rcpf(__expf(2.f*x) + 1.f);
}

// ---------------------------------------------------------------------------
// Stage 0: convert fp32 weights to bf16; LSTM weights (t<4) are row-permuted
// so that MFMA slot (wave w, n-tile n, lane mL) = gate-type n, channel w*16+mL.
// orig_row(col') = ((col'>>4)&3)*128 + ((col'>>6)<<4) + (col'&15)
// ---------------------------------------------------------------------------
struct CvtArgs { const float* s[10]; u16* d[10]; };
__global__ __launch_bounds__(256) void cvt_kernel(CvtArgs a){
  int e = (blockIdx.x*256 + threadIdx.x)*4;
  if (e >= 1114112) return;
  int t, off;
  if (e < 262144){ t = e>>16; off = e & 65535; }
  else if (e < 327680){ int e2=e-262144; t = 4+(e2>>15); off = e2&32767; }
  else { int e3=e-327680; t = 6 + e3/196608; off = e3%196608; }
  int src = off;
  if (t < 4){
    int colp = off>>7, k = off&127;
    int orig = ((colp>>4)&3)*128 + ((colp>>6)<<4) + (colp&15);
    src = orig*128 + k;
  }
  f32x4 v = *reinterpret_cast<const f32x4*>(a.s[t]+src);
  s16x4 o;
  #pragma unroll
  for (int i=0;i<4;i++) o[i]=(short)f2bf(v[i]);
  *reinterpret_cast<s16x4*>(a.d[t]+off) = o;
}

// ---------------------------------------------------------------------------
// Stage 0b: compact active-partner lists (round-invariant). One block per row;
// slot claimed via LDS atomic (order arbitrary — pair sum is commutative).
// ---------------------------------------------------------------------------
__global__ __launch_bounds__(128) void build_lists(
    const int* __restrict__ par, const int* __restrict__ chi,
    const float* __restrict__ mask,
    int2* __restrict__ ent0, int* __restrict__ cnt0,
    int2* __restrict__ ent1, int* __restrict__ cnt1)
{
  const int rr = blockIdx.x;
  __shared__ int c0s, c1s;
  if (threadIdx.x==0){ c0s=0; c1s=0; }
  __syncthreads();
  const int l = threadIdx.x;
  if (l < S_){
    const int b = rr/S_, fx = rr%S_, base = b*S_*S_;
    int idx = base + l*S_ + fx;
    if (mask[idx] != 0.f){
      int p = atomicAdd(&c0s, 1);
      ent0[rr*S_ + p] = make_int2(chi[idx], par[idx]);
    }
    int jdx = base + fx*S_ + l;
    if (mask[jdx] != 0.f){
      int p = atomicAdd(&c1s, 1);
      ent1[rr*S_ + p] = make_int2(par[jdx], chi[jdx]);
    }
  }
  __syncthreads();
  if (threadIdx.x==0){ cnt0[rr]=c0s; cnt1[rr]=c1s; }
}

// ---------------------------------------------------------------------------
// Stage 1: bidirectional LSTM final states. 16 seqs/block, 8 waves, weights
// register-resident (asm-pinned). Gate-permuted weights -> all 4 gates of a
// (seq,ch) in one lane; cell update pure-register; distance-2 emb prefetch.
// LDS row: [x0|x1|h0|h1] 128 shorts each, stride XROW=530.
// ---------------------------------------------------------------------------
__global__ __launch_bounds__(512, 2) void lstm_kernel(
    const int* __restrict__ enc, const float* __restrict__ emb,
    const u16* __restrict__ WihF, const u16* __restrict__ WhhF, const float* __restrict__ bF,
    const u16* __restrict__ WihB, const u16* __restrict__ WhhB, const float* __restrict__ bB,
    u16* __restrict__ c_cat, u16* __restrict__ h_cat)
{
  __shared__ short xh[16*XROW];
  __shared__ int   toks[16*T_];

  const int tid  = threadIdx.x;
  const int wave = tid>>6;
  const int lane = tid&63;
  const int dir  = blockIdx.y;
  const int s0   = blockIdx.x*16;

  const u16* Wih = dir ? WihB : WihF;
  const u16* Whh = dir ? WhhB : WhhF;
  const float* bb = dir ? bB  : bF;

  for (int i=tid; i<16*T_; i+=512)
    toks[i] = enc[(s0 + i/T_)*T_ + (i%T_)];

  const int mL   = lane&15;
  const int quad = lane>>4;
  const int kb   = quad*8;

  // permuted weight fragments, pinned in registers
  bf8 Breg[4][8];
  float bias[4];
  #pragma unroll
  for (int n=0;n<4;n++){
    int colp = wave*64 + n*16 + mL;
    bias[n] = bb[n*128 + wave*16 + mL];
    #pragma unroll
    for (int ks=0;ks<8;ks++){
      int k = ks*32 + kb;
      const u16* p = (k<128) ? (Wih + colp*128 + k) : (Whh + colp*128 + (k-128));
      Breg[n][ks] = *reinterpret_cast<const bf8*>(p);
      asm volatile("" : "+v"(Breg[n][ks]));
    }
  }

  // zero h0 region
  if (tid<256){
    int r = tid>>4, c = tid&15;
    *reinterpret_cast<i32x4*>(&xh[r*XROW + 256 + c*8]) = (i32x4){0,0,0,0};
  }

  const int srow = tid>>5, schunk = tid&31;   // staging map (512 threads)
  float cst[4] = {0.f,0.f,0.f,0.f};
  float hst[4] = {0.f,0.f,0.f,0.f};

  __syncthreads();  // toks + zero-h0 visible

  { // stage x[0] directly
    int tok = toks[srow*T_ + (dir ? (T_-1) : 0)];
    f32x4 xv = *reinterpret_cast<const f32x4*>(emb + tok*128 + schunk*4);
    s16x4 xp;
    #pragma unroll
    for (int i=0;i<4;i++) xp[i]=(short)f2bf(xv[i]);
    *reinterpret_cast<s16x4*>(&xh[srow*XROW + schunk*4]) = xp;
  }
  // preload x(1), x(2) into registers (distance-2 pipeline)
  f32x4 xv1, xv2;
  {
    int tok1 = toks[srow*T_ + (dir ? (T_-2) : 1)];
    xv1 = *reinterpret_cast<const f32x4*>(emb + tok1*128 + schunk*4);
    int tok2 = toks[srow*T_ + (dir ? (T_-3) : 2)];
    xv2 = *reinterpret_cast<const f32x4*>(emb + tok2*128 + schunk*4);
  }
  __syncthreads();

  for (int t=0;t<T_;t++){
    const int cb = t&1, nb2 = (t+1)&1;
    // store x(t+1) (loaded 2 steps ago) into the nb2 x-buffer
    if (t+1 < T_){
      s16x4 xp;
      #pragma unroll
      for (int i=0;i<4;i++) xp[i]=(short)f2bf(xv1[i]);
      *reinterpret_cast<s16x4*>(&xh[srow*XROW + nb2*128 + schunk*4]) = xp;
    }
    xv1 = xv2;
    if (t+3 < T_){
      int tok = toks[srow*T_ + (dir ? (T_-4-t) : (t+3))];
      xv2 = *reinterpret_cast<const f32x4*>(emb + tok*128 + schunk*4);
    }

    f32x4 acc[4];
    #pragma unroll
    for (int i=0;i<4;i++) acc[i] = (f32x4){0.f,0.f,0.f,0.f};
    #pragma unroll
    for (int ks=0;ks<8;ks++){
      int k = ks*32 + kb;
      int off = (k<128) ? (cb*128 + k) : (256 + cb*128 + (k-128));
      bf8 a = *reinterpret_cast<const bf8*>(&xh[mL*XROW + off]);
      #pragma unroll
      for (int n=0;n<4;n++)
        acc[n] = __builtin_amdgcn_mfma_f32_16x16x32_bf16(a, Breg[n][ks], acc[n], 0,0,0);
    }

    // cell update in registers; h(t+1) -> LDS h[nb2]
    #pragma unroll
    for (int i=0;i<4;i++){
      float gi_ = acc[0][i]+bias[0];
      float gf_ = acc[1][i]+bias[1];
      float gg_ = acc[2][i]+bias[2];
      float go_ = acc[3][i]+bias[3];
      float c = sigm(gf_)*cst[i] + sigm(gi_)*tanh_(gg_);
      float h = sigm(go_)*tanh_(c);
      cst[i]=c; hst[i]=h;
      xh[(quad*4+i)*XROW + 256 + nb2*128 + wave*16 + mL] = (short)f2bf(h);
    }
    __syncthreads();
  }

  {
    const int ch = wave*16 + mL;
    #pragma unroll
    for (int i=0;i<4;i++){
      int gs = s0 + quad*4 + i;
      c_cat[gs*256 + dir*128 + ch] = f2bf(cst[i]);
      h_cat[gs*256 + dir*128 + ch] = f2bf(hst[i]);
    }
  }
}

// ---------------------------------------------------------------------------
// Stage 2: enc_states = [relu([cf|cb]@Wc.T+bc) | relu([hf|hb]@Whr.T+bhr)]
// -> hidden fp32 + bf16 mirror; row 0 zeroed.
// ---------------------------------------------------------------------------
__global__ __launch_bounds__(256) void reduce_kernel(
    const u16* __restrict__ c_cat, const u16* __restrict__ h_cat,
    const u16* __restrict__ Wc, const float* __restrict__ bc,
    const u16* __restrict__ Whr, const float* __restrict__ bhr,
    float* __restrict__ hidf, u16* __restrict__ hidb)
{
  const int tid=threadIdx.x, wave=tid>>6, lane=tid&63;
  const int mL=lane&15, quad=lane>>4, kb=quad*8;
  const int m0 = blockIdx.x*64;
  const u16* A    = (wave<2) ? c_cat : h_cat;
  const u16* W    = (wave<2) ? Wc  : Whr;
  const float* bv = (wave<2) ? bc  : bhr;
  const int nb    = (wave&1)*64;
  const int obase = (wave<2) ? 0 : 128;

  f32x4 acc[4][4];
  #pragma unroll
  for (int mt=0;mt<4;mt++)
    #pragma unroll
    for (int nt=0;nt<4;nt++) acc[mt][nt] = (f32x4){0.f,0.f,0.f,0.f};

  #pragma unroll
  for (int ks=0;ks<8;ks++){
    int k = ks*32 + kb;
    bf8 bfr[4];
    #pragma unroll
    for (int nt=0;nt<4;nt++)
      bfr[nt] = *reinterpret_cast<const bf8*>(W + (nb+nt*16+mL)*256 + k);
    #pragma unroll
    for (int mt=0;mt<4;mt++){
      bf8 a = *reinterpret_cast<const bf8*>(A + (m0+mt*16+mL)*256 + k);
      #pragma unroll
      for (int nt=0;nt<4;nt++)
        acc[mt][nt] = __builtin_amdgcn_mfma_f32_16x16x32_bf16(a, bfr[nt], acc[mt][nt], 0,0,0);
    }
  }
  const int row0 = quad*4;
  float biasv[4];
  #pragma unroll
  for (int nt=0;nt<4;nt++) biasv[nt] = bv[nb+nt*16+mL];
  #pragma unroll
  for (int mt=0;mt<4;mt++){
    #pragma unroll
    for (int nt=0;nt<4;nt++){
      int col = obase + nb + nt*16 + mL;
      #pragma unroll
      for (int i=0;i<4;i++){
        int r = m0 + mt*16 + row0 + i;
        float v = fmaxf(acc[mt][nt][i] + biasv[nt], 0.f);
        hidf[(r+1)*256 + col] = v;
        hidb[(r+1)*256 + col] = f2bf(v);
      }
    }
  }
  if (blockIdx.x==0 && tid<64){
    #pragma unroll
    for (int j=0;j<4;j++){ hidf[tid*4+j] = 0.f; hidb[tid*4+j] = 0; }
  }
}

// ---------------------------------------------------------------------------
// Stage 3 (x4): gi = hidden@Wi.T + bi, gh = hidden@Wh.T + bh  (bf16 tables)
// ---------------------------------------------------------------------------
__global__ __launch_bounds__(256) void gates_gemm_kernel(
    const u16* __restrict__ hidb,
    const u16* __restrict__ Wi, const u16* __restrict__ Wh,
    const float* __restrict__ bi, const float* __restrict__ bh,
    u16* __restrict__ gi, u16* __restrict__ gh)
{
  const int tid=threadIdx.x, wave=tid>>6, lane=tid&63;
  const int mL=lane&15, quad=lane>>4, kb=quad*8;
  const int m0 = blockIdx.x*32;
  const int n0 = blockIdx.y*256 + wave*64;
  const bool isI = (n0 < 768);
  const u16* W    = isI ? Wi : Wh;
  const float* bv = isI ? bi : bh;
  u16* out        = isI ? gi : gh;
  const int nbc   = isI ? n0 : (n0-768);

  int arow[2];
  #pragma unroll
  for (int mt=0;mt<2;mt++) arow[mt] = min(m0+mt*16+mL, NR-1);

  f32x4 acc[2][4];
  #pragma unroll
  for (int mt=0;mt<2;mt++)
    #pragma unroll
    for (int nt=0;nt<4;nt++) acc[mt][nt] = (f32x4){0.f,0.f,0.f,0.f};

  #pragma unroll
  for (int ks=0;ks<8;ks++){
    int k = ks*32 + kb;
    bf8 bfr[4];
    #pragma unroll
    for (int nt=0;nt<4;nt++)
      bfr[nt] = *reinterpret_cast<const bf8*>(W + (nbc+nt*16+mL)*256 + k);
    #pragma unroll
    for (int mt=0;mt<2;mt++){
      bf8 a = *reinterpret_cast<const bf8*>(hidb + arow[mt]*256 + k);
      #pragma unroll
      for (int nt=0;nt<4;nt++)
        acc[mt][nt] = __builtin_amdgcn_mfma_f32_16x16x32_bf16(a, bfr[nt], acc[mt][nt], 0,0,0);
    }
  }
  const int row0 = quad*4;
  float biasv[4];
  #pragma unroll
  for (int nt=0;nt<4;nt++) biasv[nt] = bv[nbc+nt*16+mL];
  #pragma unroll
  for (int mt=0;mt<2;mt++){
    #pragma unroll
    for (int nt=0;nt<4;nt++){
      #pragma unroll
      for (int i=0;i<4;i++){
        int r = m0 + mt*16 + row0 + i;
        if (r < NR)
          out[r*768 + nbc + nt*16 + mL] = f2bf(acc[mt][nt][i] + biasv[nt]);
      }
    }
  }
}

// ---------------------------------------------------------------------------
// Stage 4 (x4): block per output row; partners split across 8 waves (512 thr);
// GRU elementwise fp32 (division-free); LDS cross-wave sum; L2-norm scale;
// double-buffered hidden update.
// ---------------------------------------------------------------------------
__global__ __launch_bounds__(512) void pair_kernel(
    const u16* __restrict__ gi, const u16* __restrict__ gh,
    const float* __restrict__ hin,
    float* __restrict__ hout, u16* __restrict__ bout, float* __restrict__ dout,
    const int2* __restrict__ ent, const int* __restrict__ cnt)
{
  const int r = blockIdx.x;
  const int tid = threadIdx.x, wave = tid>>6, lane = tid&63;
  __shared__ float part[8][260];
  __shared__ float ssum[4];
  if (r==0){
    if (tid<256){
      hout[tid]=0.f; bout[tid]=0;
      if (dout) dout[tid]=0.f;
    }
    return;
  }
  const int rr = r-1;
  const int n  = cnt[rr];
  const int2* e = ent + rr*S_;
  const int ch0 = lane*4;

  float a0=0.f, a1=0.f, a2=0.f, a3=0.f;
  for (int k=wave; k<n; k+=8){
    int2 pr = e[k];
    const u16* gx = gi + pr.x*768 + ch0;
    const u16* gy = gh + pr.y*768 + ch0;
    s16x4 vi0 = *reinterpret_cast<const s16x4*>(gx);
    s16x4 vi1 = *reinterpret_cast<const s16x4*>(gx+256);
    s16x4 vi2 = *reinterpret_cast<const s16x4*>(gx+512);
    s16x4 vh0 = *reinterpret_cast<const s16x4*>(gy);
    s16x4 vh1 = *reinterpret_cast<const s16x4*>(gy+256);
    s16x4 vh2 = *reinterpret_cast<const s16x4*>(gy+512);
    f32x4 hv  = *reinterpret_cast<const f32x4*>(hin + pr.y*256 + ch0);
    float o[4];
    #pragma unroll
    for (int i=0;i<4;i++){
      float rg = sigm(bf2f((u16)vi0[i]) + bf2f((u16)vh0[i]));
      float zg = sigm(bf2f((u16)vi1[i]) + bf2f((u16)vh1[i]));
      float ng = tanh_(bf2f((u16)vi2[i]) + rg*bf2f((u16)vh2[i]));
      o[i] = (1.f-zg)*ng + zg*hv[i];
    }
    a0 += o[0]; a1 += o[1]; a2 += o[2]; a3 += o[3];
  }
  *reinterpret_cast<f32x4*>(&part[wave][ch0]) = (f32x4){a0,a1,a2,a3};
  __syncthreads();

  if (tid < 256){
    float tot = part[0][tid] + part[1][tid] + part[2][tid] + part[3][tid]
              + part[4][tid] + part[5][tid] + part[6][tid] + part[7][tid];
    part[0][tid] = tot;                 // stash for epilogue
    float sq = tot*tot;
    #pragma unroll
    for (int off=32; off>0; off>>=1) sq += __shfl_xor(sq, off, 64);
    if (lane==0) ssum[wave] = sq;
  }
  __syncthreads();
  if (tid < 256){
    float tot = part[0][tid];
    float v  = sqrtf(ssum[0]+ssum[1]+ssum[2]+ssum[3]);
    float sc = (v + 0.25f)*__builtin_amdgcn_rcpf(v + 1.f);
    float nv = hin[r*256 + tid] + tot*sc;
    hout[r*256 + tid] = nv;
    bout[r*256 + tid] = f2bf(nv);
    if (dout) dout[r*256 + tid] = nv;
  }
}

// ---------------------------------------------------------------------------
extern "C" void kernel_launch(void* const* d_in, const int* in_sizes, int n_in,
                              void* d_out, int out_size, void* d_ws, size_t ws_size,
                              hipStream_t stream)
{
  const int*   enc  = (const int*)  d_in[0];
  const int*   spar = (const int*)  d_in[1];
  const int*   schi = (const int*)  d_in[2];
  const float* mask = (const float*)d_in[3];
  const float* emb  = (const float*)d_in[4];
  const float* WihF = (const float*)d_in[5];
  const float* WhhF = (const float*)d_in[6];
  const float* bF   = (const float*)d_in[7];
  const float* WihB = (const float*)d_in[8];
  const float* WhhB = (const float*)d_in[9];
  const float* bB   = (const float*)d_in[10];
  const float* Wc   = (const float*)d_in[11];
  const float* bc   = (const float*)d_in[12];
  const float* Whr  = (const float*)d_in[13];
  const float* bhr  = (const float*)d_in[14];
  const float* WiCP = (const float*)d_in[15];
  const float* WhCP = (const float*)d_in[16];
  const float* biCP = (const float*)d_in[17];
  const float* bhCP = (const float*)d_in[18];
  const float* WiPC = (const float*)d_in[19];
  const float* WhPC = (const float*)d_in[20];
  const float* biPC = (const float*)d_in[21];
  const float* bhPC = (const float*)d_in[22];

  // workspace layout (~14.8 MB)
  char* ws = (char*)d_ws;
  u16*   c_cat = (u16*)  (ws + 0);          // 1536*256 bf16
  u16*   h_cat = (u16*)  (ws + 786432);
  float* hf0   = (float*)(ws + 1572864);    // 1537*256 f32
  float* hf1   = (float*)(ws + 3146752);
  u16*   hb    = (u16*)  (ws + 4720640);    // 1537*256 bf16 (single buffer)
  u16*   gi    = (u16*)  (ws + 5507584);    // 1537*768 bf16
  u16*   gh    = (u16*)  (ws + 7868416);
  u16*   wbf   = (u16*)  (ws + 10229248);   // bf16 weights (1114112 elems)
  int2*  ent0  = (int2*) (ws + 12457472);   // 1536*96 int2
  int2*  ent1  = (int2*) (ws + 13637120);
  int*   cnt0  = (int*)  (ws + 14816768);
  int*   cnt1  = (int*)  (ws + 14822912);
  float* out   = (float*)d_out;

  u16* bWihF = wbf + 0;
  u16* bWhhF = wbf + 65536;
  u16* bWihB = wbf + 131072;
  u16* bWhhB = wbf + 196608;
  u16* bWc   = wbf + 262144;
  u16* bWhr  = wbf + 294912;
  u16* bWiCP = wbf + 327680;
  u16* bWhCP = wbf + 524288;
  u16* bWiPC = wbf + 720896;
  u16* bWhPC = wbf + 917504;

  CvtArgs ca;
  ca.s[0]=WihF; ca.s[1]=WhhF; ca.s[2]=WihB; ca.s[3]=WhhB;
  ca.s[4]=Wc;   ca.s[5]=Whr;
  ca.s[6]=WiCP; ca.s[7]=WhCP; ca.s[8]=WiPC; ca.s[9]=WhPC;
  ca.d[0]=bWihF; ca.d[1]=bWhhF; ca.d[2]=bWihB; ca.d[3]=bWhhB;
  ca.d[4]=bWc;   ca.d[5]=bWhr;
  ca.d[6]=bWiCP; ca.d[7]=bWhCP; ca.d[8]=bWiPC; ca.d[9]=bWhPC;
  cvt_kernel<<<dim3(1088), dim3(256), 0, stream>>>(ca);
  build_lists<<<dim3(NSEQ), dim3(128), 0, stream>>>(spar, schi, mask, ent0, cnt0, ent1, cnt1);

  lstm_kernel<<<dim3(96,2), dim3(512), 0, stream>>>(
      enc, emb, bWihF,bWhhF,bF, bWihB,bWhhB,bB, c_cat, h_cat);
  reduce_kernel<<<dim3(24), dim3(256), 0, stream>>>(
      c_cat,h_cat, bWc,bc,bWhr,bhr, hf0,hb);

  float* hfb[2] = {hf0,hf1};
  int cur = 0;
  for (int it=0; it<4; it++){
    const u16* Wi   = (it<2)?bWiCP:bWiPC;
    const u16* Wh   = (it<2)?bWhCP:bWhPC;
    const float* bi = (it<2)?biCP:biPC;
    const float* bh = (it<2)?bhCP:bhPC;
    int nxt = cur^1;
    gates_gemm_kernel<<<dim3(49,6), dim3(256), 0, stream>>>(
        hb, Wi,Wh,bi,bh, gi,gh);
    pair_kernel<<<dim3(NR), dim3(512), 0, stream>>>(
        gi,gh, hfb[cur], hfb[nxt], hb,
        (it==3)?out:(float*)nullptr,
        (it<2)?ent0:ent1, (it<2)?cnt0:cnt1);
    cur = nxt;
  }
}

// Round 6
// 325.873 us; speedup vs baseline: 1.5111x; 1.0242x over previous
//
#include <hip/hip_runtime.h>

typedef unsigned short u16;
typedef __attribute__((ext_vector_type(8))) short bf8;    // 8 x bf16 MFMA fragment
typedef __attribute__((ext_vector_type(4))) short s16x4;
typedef __attribute__((ext_vector_type(4))) float f32x4;
typedef __attribute__((ext_vector_type(4))) int   i32x4;

#define S_   96
#define T_   50
#define NSEQ 1536
#define NR   1537
#define XROW 520   // LDS row stride in shorts: 1040 B, 16B-aligned, 260 dwords
// hidden width 256, gate width 768

__device__ __forceinline__ float bf2f(u16 u){ return __uint_as_float(((unsigned)u)<<16); }
__device__ __forceinline__ u16 f2bf(float f){
  unsigned u = __float_as_uint(f);
  u += 0x7fffu + ((u>>16)&1u);           // RNE
  return (u16)(u>>16);
}
// division-free; fine vs 2% threshold, NaN-safe at +-inf
__device__ __forceinline__ float sigm(float x){
  return __builtin_amdgcn_rcpf(1.f + __expf(-x));
}
__device__ __forceinline__ float tanh_(float x){
  return 1.f - 2.f*__builtin_amdgcn_rcpf(__expf(2.f*x) + 1.f);
}
// barrier that drains only LDS (lgkm), NOT in-flight global prefetch (vmcnt).
// __syncthreads would emit s_waitcnt vmcnt(0) and kill the distance-2 pipeline.
__device__ __forceinline__ void bar_lds(){
  asm volatile("s_waitcnt lgkmcnt(0)\n\ts_barrier" ::: "memory");
}

// ---------------------------------------------------------------------------
// Stage 0 (fused): blocks [0,1088) convert fp32 weights to bf16 (LSTM weights
// row-permuted: permuted col c' -> gate-type (c'>>4)&3, channel (c'>>6)*16 +
// (c'&15)); blocks [1088, 1088+NSEQ) build compacted active-partner lists.
// ---------------------------------------------------------------------------
struct CvtArgs { const float* s[10]; u16* d[10]; };
__global__ __launch_bounds__(256) void prep_kernel(CvtArgs a,
    const int* __restrict__ par, const int* __restrict__ chi,
    const float* __restrict__ mask,
    int2* __restrict__ ent0, int* __restrict__ cnt0,
    int2* __restrict__ ent1, int* __restrict__ cnt1)
{
  if (blockIdx.x < 1088){
    int e = (blockIdx.x*256 + threadIdx.x)*4;
    if (e >= 1114112) return;
    int t, off;
    if (e < 262144){ t = e>>16; off = e & 65535; }
    else if (e < 327680){ int e2=e-262144; t = 4+(e2>>15); off = e2&32767; }
    else { int e3=e-327680; t = 6 + e3/196608; off = e3%196608; }
    int src = off;
    if (t < 4){
      int colp = off>>7, k = off&127;
      int orig = ((colp>>4)&3)*128 + ((colp>>6)<<4) + (colp&15);
      src = orig*128 + k;
    }
    f32x4 v = *reinterpret_cast<const f32x4*>(a.s[t]+src);
    s16x4 o;
    #pragma unroll
    for (int i=0;i<4;i++) o[i]=(short)f2bf(v[i]);
    *reinterpret_cast<s16x4*>(a.d[t]+off) = o;
  } else {
    const int rr = blockIdx.x - 1088;
    __shared__ int c0s, c1s;
    if (threadIdx.x==0){ c0s=0; c1s=0; }
    __syncthreads();
    const int l = threadIdx.x;
    if (l < S_){
      const int b = rr/S_, fx = rr%S_, base = b*S_*S_;
      int idx = base + l*S_ + fx;
      if (mask[idx] != 0.f){
        int p = atomicAdd(&c0s, 1);
        ent0[rr*S_ + p] = make_int2(chi[idx], par[idx]);
      }
      int jdx = base + fx*S_ + l;
      if (mask[jdx] != 0.f){
        int p = atomicAdd(&c1s, 1);
        ent1[rr*S_ + p] = make_int2(par[jdx], chi[jdx]);
      }
    }
    __syncthreads();
    if (threadIdx.x==0){ cnt0[rr]=c0s; cnt1[rr]=c1s; }
  }
}

// ---------------------------------------------------------------------------
// Stage 1: bidirectional LSTM final states. 16 seqs/block, 8 waves, weights
// register-resident (asm-pinned), MFMA operands SWAPPED (A=weights, B=x|h):
// D[row=quad*4+i -> channel w*16+quad*4+i][col=mL -> seq]. Each lane owns all
// 4 gates of 4 consecutive channels of one seq -> h-write is ONE ds_write_b64.
// Distance-2 emb prefetch + lgkm-only barrier keeps gathers in flight.
// LDS row: [x0|x1|h0|h1] 128 shorts each, stride XROW=520 (16B aligned).
// ---------------------------------------------------------------------------
__global__ __launch_bounds__(512, 2) void lstm_kernel(
    const int* __restrict__ enc, const float* __restrict__ emb,
    const u16* __restrict__ WihF, const u16* __restrict__ WhhF, const float* __restrict__ bF,
    const u16* __restrict__ WihB, const u16* __restrict__ WhhB, const float* __restrict__ bB,
    u16* __restrict__ c_cat, u16* __restrict__ h_cat)
{
  __shared__ short xh[16*XROW];
  __shared__ int   toks[16*T_];

  const int tid  = threadIdx.x;
  const int wave = tid>>6;
  const int lane = tid&63;
  const int dir  = blockIdx.y;
  const int s0   = blockIdx.x*16;

  const u16* Wih = dir ? WihB : WihF;
  const u16* Whh = dir ? WhhB : WhhF;
  const float* bb = dir ? bB  : bF;

  for (int i=tid; i<16*T_; i+=512)
    toks[i] = enc[(s0 + i/T_)*T_ + (i%T_)];

  const int mL   = lane&15;
  const int quad = lane>>4;
  const int kb   = quad*8;

  // permuted weight fragments (A-operand layout: m=mL, k=quad*8+j), pinned
  bf8 Breg[4][8];
  f32x4 bias4[4];
  #pragma unroll
  for (int n=0;n<4;n++){
    int colp = wave*64 + n*16 + mL;
    bias4[n] = *reinterpret_cast<const f32x4*>(bb + n*128 + wave*16 + quad*4);
    #pragma unroll
    for (int ks=0;ks<8;ks++){
      int k = ks*32 + kb;
      const u16* p = (k<128) ? (Wih + colp*128 + k) : (Whh + colp*128 + (k-128));
      Breg[n][ks] = *reinterpret_cast<const bf8*>(p);
      asm volatile("" : "+v"(Breg[n][ks]));
    }
  }

  // zero h0 region
  if (tid<256){
    int r = tid>>4, c = tid&15;
    *reinterpret_cast<i32x4*>(&xh[r*XROW + 256 + c*8]) = (i32x4){0,0,0,0};
  }

  const int srow = tid>>5, schunk = tid&31;   // staging map (512 threads)
  float cst[4] = {0.f,0.f,0.f,0.f};
  float hst[4] = {0.f,0.f,0.f,0.f};

  __syncthreads();  // toks + zero-h0 visible

  { // stage x[0] directly
    int tok = toks[srow*T_ + (dir ? (T_-1) : 0)];
    f32x4 xv = *reinterpret_cast<const f32x4*>(emb + tok*128 + schunk*4);
    s16x4 xp;
    #pragma unroll
    for (int i=0;i<4;i++) xp[i]=(short)f2bf(xv[i]);
    *reinterpret_cast<s16x4*>(&xh[srow*XROW + schunk*4]) = xp;
  }
  // preload x(1), x(2) into registers (distance-2 pipeline)
  f32x4 xv1, xv2;
  {
    int tok1 = toks[srow*T_ + (dir ? (T_-2) : 1)];
    xv1 = *reinterpret_cast<const f32x4*>(emb + tok1*128 + schunk*4);
    int tok2 = toks[srow*T_ + (dir ? (T_-3) : 2)];
    xv2 = *reinterpret_cast<const f32x4*>(emb + tok2*128 + schunk*4);
  }
  __syncthreads();

  for (int t=0;t<T_;t++){
    const int cb = t&1, nb2 = (t+1)&1;
    // store x(t+1) (loaded 2 steps ago) into the nb2 x-buffer
    if (t+1 < T_){
      s16x4 xp;
      #pragma unroll
      for (int i=0;i<4;i++) xp[i]=(short)f2bf(xv1[i]);
      *reinterpret_cast<s16x4*>(&xh[srow*XROW + nb2*128 + schunk*4]) = xp;
    }
    xv1 = xv2;
    if (t+3 < T_){
      int tok = toks[srow*T_ + (dir ? (T_-4-t) : (t+3))];
      xv2 = *reinterpret_cast<const f32x4*>(emb + tok*128 + schunk*4);
    }

    f32x4 acc[4];
    #pragma unroll
    for (int i=0;i<4;i++) acc[i] = (f32x4){0.f,0.f,0.f,0.f};
    #pragma unroll
    for (int ks=0;ks<8;ks++){
      int k = ks*32 + kb;
      int off = (k<128) ? (cb*128 + k) : (256 + cb*128 + (k-128));
      bf8 b = *reinterpret_cast<const bf8*>(&xh[mL*XROW + off]);
      #pragma unroll
      for (int n=0;n<4;n++)
        acc[n] = __builtin_amdgcn_mfma_f32_16x16x32_bf16(Breg[n][ks], b, acc[n], 0,0,0);
    }

    // cell update: lane owns channels wave*16+quad*4+i of seq mL
    s16x4 hp;
    #pragma unroll
    for (int i=0;i<4;i++){
      float gi_ = acc[0][i]+bias4[0][i];
      float gf_ = acc[1][i]+bias4[1][i];
      float gg_ = acc[2][i]+bias4[2][i];
      float go_ = acc[3][i]+bias4[3][i];
      float c = sigm(gf_)*cst[i] + sigm(gi_)*tanh_(gg_);
      float h = sigm(go_)*tanh_(c);
      cst[i]=c; hst[i]=h;
      hp[i] = (short)f2bf(h);
    }
    *reinterpret_cast<s16x4*>(&xh[mL*XROW + 256 + nb2*128 + wave*16 + quad*4]) = hp;
    bar_lds();
  }

  {
    const int ch = wave*16 + quad*4;
    const int gs = s0 + mL;
    s16x4 cp_, hp_;
    #pragma unroll
    for (int i=0;i<4;i++){ cp_[i]=(short)f2bf(cst[i]); hp_[i]=(short)f2bf(hst[i]); }
    *reinterpret_cast<s16x4*>(c_cat + gs*256 + dir*128 + ch) = cp_;
    *reinterpret_cast<s16x4*>(h_cat + gs*256 + dir*128 + ch) = hp_;
  }
}

// ---------------------------------------------------------------------------
// Stage 2: enc_states = [relu([cf|cb]@Wc.T+bc) | relu([hf|hb]@Whr.T+bhr)]
// -> hidden fp32 + bf16 mirror; row 0 zeroed.
// ---------------------------------------------------------------------------
__global__ __launch_bounds__(256) void reduce_kernel(
    const u16* __restrict__ c_cat, const u16* __restrict__ h_cat,
    const u16* __restrict__ Wc, const float* __restrict__ bc,
    const u16* __restrict__ Whr, const float* __restrict__ bhr,
    float* __restrict__ hidf, u16* __restrict__ hidb)
{
  const int tid=threadIdx.x, wave=tid>>6, lane=tid&63;
  const int mL=lane&15, quad=lane>>4, kb=quad*8;
  const int m0 = blockIdx.x*64;
  const u16* A    = (wave<2) ? c_cat : h_cat;
  const u16* W    = (wave<2) ? Wc  : Whr;
  const float* bv = (wave<2) ? bc  : bhr;
  const int nb    = (wave&1)*64;
  const int obase = (wave<2) ? 0 : 128;

  f32x4 acc[4][4];
  #pragma unroll
  for (int mt=0;mt<4;mt++)
    #pragma unroll
    for (int nt=0;nt<4;nt++) acc[mt][nt] = (f32x4){0.f,0.f,0.f,0.f};

  #pragma unroll
  for (int ks=0;ks<8;ks++){
    int k = ks*32 + kb;
    bf8 bfr[4];
    #pragma unroll
    for (int nt=0;nt<4;nt++)
      bfr[nt] = *reinterpret_cast<const bf8*>(W + (nb+nt*16+mL)*256 + k);
    #pragma unroll
    for (int mt=0;mt<4;mt++){
      bf8 a = *reinterpret_cast<const bf8*>(A + (m0+mt*16+mL)*256 + k);
      #pragma unroll
      for (int nt=0;nt<4;nt++)
        acc[mt][nt] = __builtin_amdgcn_mfma_f32_16x16x32_bf16(a, bfr[nt], acc[mt][nt], 0,0,0);
    }
  }
  const int row0 = quad*4;
  float biasv[4];
  #pragma unroll
  for (int nt=0;nt<4;nt++) biasv[nt] = bv[nb+nt*16+mL];
  #pragma unroll
  for (int mt=0;mt<4;mt++){
    #pragma unroll
    for (int nt=0;nt<4;nt++){
      int col = obase + nb + nt*16 + mL;
      #pragma unroll
      for (int i=0;i<4;i++){
        int r = m0 + mt*16 + row0 + i;
        float v = fmaxf(acc[mt][nt][i] + biasv[nt], 0.f);
        hidf[(r+1)*256 + col] = v;
        hidb[(r+1)*256 + col] = f2bf(v);
      }
    }
  }
  if (blockIdx.x==0 && tid<64){
    #pragma unroll
    for (int j=0;j<4;j++){ hidf[tid*4+j] = 0.f; hidb[tid*4+j] = 0; }
  }
}

// ---------------------------------------------------------------------------
// Stage 3 (x4): gi = hidden@Wi.T + bi, gh = hidden@Wh.T + bh  (bf16 tables)
// ---------------------------------------------------------------------------
__global__ __launch_bounds__(256) void gates_gemm_kernel(
    const u16* __restrict__ hidb,
    const u16* __restrict__ Wi, const u16* __restrict__ Wh,
    const float* __restrict__ bi, const float* __restrict__ bh,
    u16* __restrict__ gi, u16* __restrict__ gh)
{
  const int tid=threadIdx.x, wave=tid>>6, lane=tid&63;
  const int mL=lane&15, quad=lane>>4, kb=quad*8;
  const int m0 = blockIdx.x*32;
  const int n0 = blockIdx.y*256 + wave*64;
  const bool isI = (n0 < 768);
  const u16* W    = isI ? Wi : Wh;
  const float* bv = isI ? bi : bh;
  u16* out        = isI ? gi : gh;
  const int nbc   = isI ? n0 : (n0-768);

  int arow[2];
  #pragma unroll
  for (int mt=0;mt<2;mt++) arow[mt] = min(m0+mt*16+mL, NR-1);

  f32x4 acc[2][4];
  #pragma unroll
  for (int mt=0;mt<2;mt++)
    #pragma unroll
    for (int nt=0;nt<4;nt++) acc[mt][nt] = (f32x4){0.f,0.f,0.f,0.f};

  #pragma unroll
  for (int ks=0;ks<8;ks++){
    int k = ks*32 + kb;
    bf8 bfr[4];
    #pragma unroll
    for (int nt=0;nt<4;nt++)
      bfr[nt] = *reinterpret_cast<const bf8*>(W + (nbc+nt*16+mL)*256 + k);
    #pragma unroll
    for (int mt=0;mt<2;mt++){
      bf8 a = *reinterpret_cast<const bf8*>(hidb + arow[mt]*256 + k);
      #pragma unroll
      for (int nt=0;nt<4;nt++)
        acc[mt][nt] = __builtin_amdgcn_mfma_f32_16x16x32_bf16(a, bfr[nt], acc[mt][nt], 0,0,0);
    }
  }
  const int row0 = quad*4;
  float biasv[4];
  #pragma unroll
  for (int nt=0;nt<4;nt++) biasv[nt] = bv[nbc+nt*16+mL];
  #pragma unroll
  for (int mt=0;mt<2;mt++){
    #pragma unroll
    for (int nt=0;nt<4;nt++){
      #pragma unroll
      for (int i=0;i<4;i++){
        int r = m0 + mt*16 + row0 + i;
        if (r < NR)
          out[r*768 + nbc + nt*16 + mL] = f2bf(acc[mt][nt][i] + biasv[nt]);
      }
    }
  }
}

// ---------------------------------------------------------------------------
// Stage 4 (x4): block per output row; partners split across 8 waves (512 thr);
// GRU elementwise fp32 (division-free); LDS cross-wave sum; L2-norm scale;
// double-buffered hidden update.
// ---------------------------------------------------------------------------
__global__ __launch_bounds__(512) void pair_kernel(
    const u16* __restrict__ gi, const u16* __restrict__ gh,
    const float* __restrict__ hin,
    float* __restrict__ hout, u16* __restrict__ bout, float* __restrict__ dout,
    const int2* __restrict__ ent, const int* __restrict__ cnt)
{
  const int r = blockIdx.x;
  const int tid = threadIdx.x, wave = tid>>6, lane = tid&63;
  __shared__ float part[8][260];
  __shared__ float ssum[4];
  if (r==0){
    if (tid<256){
      hout[tid]=0.f; bout[tid]=0;
      if (dout) dout[tid]=0.f;
    }
    return;
  }
  const int rr = r-1;
  const int n  = cnt[rr];
  const int2* e = ent + rr*S_;
  const int ch0 = lane*4;

  float a0=0.f, a1=0.f, a2=0.f, a3=0.f;
  for (int k=wave; k<n; k+=8){
    int2 pr = e[k];
    const u16* gx = gi + pr.x*768 + ch0;
    const u16* gy = gh + pr.y*768 + ch0;
    s16x4 vi0 = *reinterpret_cast<const s16x4*>(gx);
    s16x4 vi1 = *reinterpret_cast<const s16x4*>(gx+256);
    s16x4 vi2 = *reinterpret_cast<const s16x4*>(gx+512);
    s16x4 vh0 = *reinterpret_cast<const s16x4*>(gy);
    s16x4 vh1 = *reinterpret_cast<const s16x4*>(gy+256);
    s16x4 vh2 = *reinterpret_cast<const s16x4*>(gy+512);
    f32x4 hv  = *reinterpret_cast<const f32x4*>(hin + pr.y*256 + ch0);
    float o[4];
    #pragma unroll
    for (int i=0;i<4;i++){
      float rg = sigm(bf2f((u16)vi0[i]) + bf2f((u16)vh0[i]));
      float zg = sigm(bf2f((u16)vi1[i]) + bf2f((u16)vh1[i]));
      float ng = tanh_(bf2f((u16)vi2[i]) + rg*bf2f((u16)vh2[i]));
      o[i] = (1.f-zg)*ng + zg*hv[i];
    }
    a0 += o[0]; a1 += o[1]; a2 += o[2]; a3 += o[3];
  }
  *reinterpret_cast<f32x4*>(&part[wave][ch0]) = (f32x4){a0,a1,a2,a3};
  __syncthreads();

  if (tid < 256){
    float tot = part[0][tid] + part[1][tid] + part[2][tid] + part[3][tid]
              + part[4][tid] + part[5][tid] + part[6][tid] + part[7][tid];
    part[0][tid] = tot;                 // stash for epilogue
    float sq = tot*tot;
    #pragma unroll
    for (int off=32; off>0; off>>=1) sq += __shfl_xor(sq, off, 64);
    if (lane==0) ssum[wave] = sq;
  }
  __syncthreads();
  if (tid < 256){
    float tot = part[0][tid];
    float v  = sqrtf(ssum[0]+ssum[1]+ssum[2]+ssum[3]);
    float sc = (v + 0.25f)*__builtin_amdgcn_rcpf(v + 1.f);
    float nv = hin[r*256 + tid] + tot*sc;
    hout[r*256 + tid] = nv;
    bout[r*256 + tid] = f2bf(nv);
    if (dout) dout[r*256 + tid] = nv;
  }
}

// ---------------------------------------------------------------------------
extern "C" void kernel_launch(void* const* d_in, const int* in_sizes, int n_in,
                              void* d_out, int out_size, void* d_ws, size_t ws_size,
                              hipStream_t stream)
{
  const int*   enc  = (const int*)  d_in[0];
  const int*   spar = (const int*)  d_in[1];
  const int*   schi = (const int*)  d_in[2];
  const float* mask = (const float*)d_in[3];
  const float* emb  = (const float*)d_in[4];
  const float* WihF = (const float*)d_in[5];
  const float* WhhF = (const float*)d_in[6];
  const float* bF   = (const float*)d_in[7];
  const float* WihB = (const float*)d_in[8];
  const float* WhhB = (const float*)d_in[9];
  const float* bB   = (const float*)d_in[10];
  const float* Wc   = (const float*)d_in[11];
  const float* bc   = (const float*)d_in[12];
  const float* Whr  = (const float*)d_in[13];
  const float* bhr  = (const float*)d_in[14];
  const float* WiCP = (const float*)d_in[15];
  const float* WhCP = (const float*)d_in[16];
  const float* biCP = (const float*)d_in[17];
  const float* bhCP = (const float*)d_in[18];
  const float* WiPC = (const float*)d_in[19];
  const float* WhPC = (const float*)d_in[20];
  const float* biPC = (const float*)d_in[21];
  const float* bhPC = (const float*)d_in[22];

  // workspace layout (~14.8 MB)
  char* ws = (char*)d_ws;
  u16*   c_cat = (u16*)  (ws + 0);          // 1536*256 bf16
  u16*   h_cat = (u16*)  (ws + 786432);
  float* hf0   = (float*)(ws + 1572864);    // 1537*256 f32
  float* hf1   = (float*)(ws + 3146752);
  u16*   hb    = (u16*)  (ws + 4720640);    // 1537*256 bf16 (single buffer)
  u16*   gi    = (u16*)  (ws + 5507584);    // 1537*768 bf16
  u16*   gh    = (u16*)  (ws + 7868416);
  u16*   wbf   = (u16*)  (ws + 10229248);   // bf16 weights (1114112 elems)
  int2*  ent0  = (int2*) (ws + 12457472);   // 1536*96 int2
  int2*  ent1  = (int2*) (ws + 13637120);
  int*   cnt0  = (int*)  (ws + 14816768);
  int*   cnt1  = (int*)  (ws + 14822912);
  float* out   = (float*)d_out;

  u16* bWihF = wbf + 0;
  u16* bWhhF = wbf + 65536;
  u16* bWihB = wbf + 131072;
  u16* bWhhB = wbf + 196608;
  u16* bWc   = wbf + 262144;
  u16* bWhr  = wbf + 294912;
  u16* bWiCP = wbf + 327680;
  u16* bWhCP = wbf + 524288;
  u16* bWiPC = wbf + 720896;
  u16* bWhPC = wbf + 917504;

  CvtArgs ca;
  ca.s[0]=WihF; ca.s[1]=WhhF; ca.s[2]=WihB; ca.s[3]=WhhB;
  ca.s[4]=Wc;   ca.s[5]=Whr;
  ca.s[6]=WiCP; ca.s[7]=WhCP; ca.s[8]=WiPC; ca.s[9]=WhPC;
  ca.d[0]=bWihF; ca.d[1]=bWhhF; ca.d[2]=bWihB; ca.d[3]=bWhhB;
  ca.d[4]=bWc;   ca.d[5]=bWhr;
  ca.d[6]=bWiCP; ca.d[7]=bWhCP; ca.d[8]=bWiPC; ca.d[9]=bWhPC;
  prep_kernel<<<dim3(1088+NSEQ), dim3(256), 0, stream>>>(
      ca, spar, schi, mask, ent0, cnt0, ent1, cnt1);

  lstm_kernel<<<dim3(96,2), dim3(512), 0, stream>>>(
      enc, emb, bWihF,bWhhF,bF, bWihB,bWhhB,bB, c_cat, h_cat);
  reduce_kernel<<<dim3(24), dim3(256), 0, stream>>>(
      c_cat,h_cat, bWc,bc,bWhr,bhr, hf0,hb);

  float* hfb[2] = {hf0,hf1};
  int cur = 0;
  for (int it=0; it<4; it++){
    const u16* Wi   = (it<2)?bWiCP:bWiPC;
    const u16* Wh   = (it<2)?bWhCP:bWhPC;
    const float* bi = (it<2)?biCP:biPC;
    const float* bh = (it<2)?bhCP:bhPC;
    int nxt = cur^1;
    gates_gemm_kernel<<<dim3(49,6), dim3(256), 0, stream>>>(
        hb, Wi,Wh,bi,bh, gi,gh);
    pair_kernel<<<dim3(NR), dim3(512), 0, stream>>>(
        gi,gh, hfb[cur], hfb[nxt], hb,
        (it==3)?out:(float*)nullptr,
        (it<2)?ent0:ent1, (it<2)?cnt0:cnt1);
    cur = nxt;
  }
}